// Round 9
// baseline (3080.076 us; speedup 1.0000x reference)
//
#include <hip/hip_runtime.h>
#include <math.h>

#define CC 96
#define NP 4096
#define NHEADS 6
#define NELEMF 393216.0f
#define EPSF 1e-5f
#define NB 1024u

typedef __attribute__((ext_vector_type(8))) short bf16x8;
typedef __attribute__((ext_vector_type(4))) float f32x4;
#define MFMA16(a,b,c) __builtin_amdgcn_mfma_f32_16x16x32_bf16(a,b,c,0,0,0)

// ---- workspace layout (float offsets) ----
// ws[0..7]=st0  ws[8..15]=st1  ws[16..23]=st2  ws[32..33]=barrier (all zeroed by memset)
#define WQKV1  64
#define WQKV2  (WQKV1+13824)
#define WPROJ1 (WQKV2+13824)
#define WPROJ2 (WPROJ1+4608)
#define WMLP1  (WPROJ2+4608)
#define WMLP2  (WMLP1+18432)
#define WM2A1  (WMLP2+18432)
#define WM2A2  (WM2A1+4608)
#define WPA1T  (WM2A2+4608)
#define WBNS   (WPA1T+1152)
#define WS_Q   870784
#define WS_K   (WS_Q+786432)
#define WS_V   (WS_K+786432)
#define WS_ATTPM (WS_V+786432)
#define WS_X1  (WS_ATTPM+786432)  // hid (bf16 16384x384) exactly reuses WS_Q..WS_X1
#define WS_X2  (WS_X1+1572864)
#define WS_X3  (WS_X2+1572864)
#define WS_PA  (WS_X3+1572864)
#define WS_GAP (WS_PA+16384)
#define WS_CA  (WS_GAP+384)

__device__ __forceinline__ float gelu_f(float x){
  return 0.5f * x * (1.0f + erff(x * 0.7071067811865476f));
}
__device__ __forceinline__ float sigmoid_f(float x){
  return 1.0f / (1.0f + __expf(-x));
}
__device__ __forceinline__ unsigned short bfr(float f){
  unsigned int u = __float_as_uint(f);
  u += 0x7fffu + ((u >> 16) & 1u);
  return (unsigned short)(u >> 16);
}
__device__ __forceinline__ float bflo(unsigned int u){ return __uint_as_float(u << 16); }
__device__ __forceinline__ float bfhi(unsigned int u){ return __uint_as_float(u & 0xffff0000u); }
__device__ __forceinline__ void get_ms(const float* st, int b, float& mean, float& inv, float& stdv){
  float s = st[b], s2 = st[4+b];
  mean = s * (1.0f/NELEMF);
  float var = fmaxf(s2 * (1.0f/NELEMF) - mean*mean, 0.0f);
  stdv = sqrtf(var + EPSF);
  inv = 1.0f / stdv;
}

// ---- device-scope grid barrier (monotonic, no reset) ----
// bar[0]: cumulative arrivals; bar[1]: completed-phase generation.
__device__ __forceinline__ void gbar(unsigned int* bar, unsigned int phase){
  __syncthreads();
  if(threadIdx.x == 0){
    __threadfence();   // agent-scope release: L2 writeback across XCDs
    unsigned int a = __hip_atomic_fetch_add(&bar[0], 1u, __ATOMIC_ACQ_REL,
                                            __HIP_MEMORY_SCOPE_AGENT) + 1u;
    if(a == phase * NB)
      __hip_atomic_fetch_add(&bar[1], 1u, __ATOMIC_RELEASE, __HIP_MEMORY_SCOPE_AGENT);
    while(__hip_atomic_load(&bar[1], __ATOMIC_ACQUIRE, __HIP_MEMORY_SCOPE_AGENT) < phase)
      __builtin_amdgcn_s_sleep(2);
    __threadfence();   // agent-scope acquire: invalidate L1/L2
  }
  __syncthreads();
}

// ---- phase bodies ----
__device__ __forceinline__ void ph_prep(int gid,
    const float* q1, const float* q2, const float* p1, const float* p2,
    const float* w1, const float* w2, const float* a1, const float* a2,
    const float* pw1, const float* bg, const float* bb,
    const float* bm, const float* bv, float* ws){
  if(gid < 27648){ int n = gid/96, c = gid%96; ((unsigned short*)(ws+WQKV1))[gid] = bfr(q1[c*288+n]); }
  else if(gid < 55296){ int g = gid-27648; int n = g/96, c = g%96; ((unsigned short*)(ws+WQKV2))[g] = bfr(q2[c*288+n]); }
  else if(gid < 64512){ int g = gid-55296; int n = g/96, c = g%96; ((unsigned short*)(ws+WPROJ1))[g] = bfr(p1[c*96+n]); }
  else if(gid < 73728){ int g = gid-64512; int n = g/96, c = g%96; ((unsigned short*)(ws+WPROJ2))[g] = bfr(p2[c*96+n]); }
  else if(gid < 110592){ int g = gid-73728; ((unsigned short*)(ws+WMLP1))[g] = bfr(w1[g]); }
  else if(gid < 147456){ int g = gid-110592; ((unsigned short*)(ws+WMLP2))[g] = bfr(w2[g]); }
  else if(gid < 156672){ int g = gid-147456; ((unsigned short*)(ws+WM2A1))[g] = bfr(a1[g]); }
  else if(gid < 165888){ int g = gid-156672; ((unsigned short*)(ws+WM2A2))[g] = bfr(a2[g]); }
  else if(gid < 167040){ int g = gid-165888; int c = g/12, h = g%12; ws[WPA1T + g] = pw1[h*96+c]; }
  else if(gid < 167136){ int c = gid-167040;
    float sc = rsqrtf(bv[c] + EPSF) * bg[c];
    ws[WBNS + c] = sc;
    ws[WBNS + 96 + c] = bb[c] - bm[c]*sc;
  }
}

__device__ __forceinline__ void ph_stats(int item, const float* __restrict__ src,
                                         float* st, char* SMc){
  float* ls = (float*)SMc;
  int b = item / CC, c = item % CC;
  const float* p = src + (b*CC + c)*NP;
  float s = 0.f, s2 = 0.f;
  for(int i = threadIdx.x; i < NP; i += 256){ float v = p[i]; s += v; s2 = fmaf(v, v, s2); }
  for(int off = 32; off > 0; off >>= 1){ s += __shfl_down(s, off); s2 += __shfl_down(s2, off); }
  int wid = threadIdx.x >> 6;
  if((threadIdx.x & 63) == 0){ ls[wid] = s; ls[4+wid] = s2; }
  __syncthreads();
  if(threadIdx.x == 0){
    atomicAdd(&st[b],   ls[0]+ls[1]+ls[2]+ls[3]);
    atomicAdd(&st[4+b], ls[4]+ls[5]+ls[6]+ls[7]);
  }
  __syncthreads();
}

// fused LN + QKV GEMM: item = (m_tile, n_half); M=64, N=144 per block
__device__ __forceinline__ void ph_qkv(int it, const float* __restrict__ xin, const float* st,
    const float* lnw, const float* lnb,
    const unsigned short* __restrict__ wT, const float* qb,
    unsigned short* qo, unsigned short* ko, unsigned short* vo, char* SMc){
  unsigned short* Atl = (unsigned short*)SMc;      // 64*104*2 = 13312
  float* scl = (float*)(SMc + 13312);
  float* ofs = (float*)(SMc + 13312 + 384);
  int tid = threadIdx.x;
  int mt = it >> 1, nh = it & 1;
  int m_base = mt*64;
  int b = m_base >> 12, pxl0 = m_base & 4095;
  float mean, inv, stdv; get_ms(st, b, mean, inv, stdv);
  if(tid < 96){ float s = inv*lnw[tid]; scl[tid] = s; ofs[tid] = lnb[tid] - mean*s; }
  __syncthreads();
  const float* src = xin + (size_t)b*CC*NP + pxl0;
  for(int idx = tid; idx < 96*64; idx += 256){
    int c = idx >> 6, p = idx & 63;
    Atl[p*104 + c] = bfr(fmaf(src[c*NP + p], scl[c], ofs[c]));
  }
  __syncthreads();
  int w = tid >> 6, lane = tid & 63, ml = lane & 15, q = lane >> 4;
  const unsigned short* arow = Atl + (w*16 + ml)*104;
  bf16x8 av[3];
  #pragma unroll
  for(int ks = 0; ks < 3; ++ks) av[ks] = *(const bf16x8*)(arow + ks*32 + q*8);
  f32x4 z = {0.f,0.f,0.f,0.f};
  #pragma unroll
  for(int g = 0; g < 3; ++g){
    f32x4 acc[3] = {z, z, z};
    #pragma unroll
    for(int ks = 0; ks < 3; ++ks){
      #pragma unroll
      for(int gg = 0; gg < 3; ++gg){
        bf16x8 bv = *(const bf16x8*)(wT + (nh*144 + g*48 + gg*16 + ml)*96 + ks*32 + q*8);
        acc[gg] = MFMA16(av[ks], bv, acc[gg]);
      }
    }
    #pragma unroll
    for(int gg = 0; gg < 3; ++gg){
      int nfb = nh*144 + g*48 + gg*16;
      int t = nfb/96, head = (nfb%96) >> 4;
      float scale = (t == 0) ? 0.25f : 1.0f;
      unsigned short* dst = (t == 0) ? qo : (t == 1) ? ko : vo;
      float bias = qb[nfb + ml];
      #pragma unroll
      for(int r = 0; r < 4; ++r){
        int pxl = pxl0 + w*16 + q*4 + r;
        dst[(((size_t)(b*NHEADS + head))*NP + pxl)*16 + ml] = bfr((acc[gg][r] + bias)*scale);
      }
    }
  }
  __syncthreads();
}

// neighborhood attention: item = (bh, x-row); bf16 LDS-staged k/v
template<int K, int D, int RPB>
__device__ __forceinline__ void ph_attn(int item,
    const unsigned short* __restrict__ qb, const unsigned short* __restrict__ kb,
    const unsigned short* __restrict__ vb, const float* __restrict__ rpb,
    unsigned short* __restrict__ outp, char* SMc){
  int bh = item >> 6;
  int x = item & 63;
  int head = bh % NHEADS, b = bh / NHEADS;

  int gx = x % D, px = x / D;
  int Lgx = (64 - gx + D - 1) / D;
  int sx = min(max(px - K/2, 0), Lgx - K);

  unsigned int* kl = (unsigned int*)SMc;
  unsigned int* vl = kl + K*512;
  const unsigned int* kg = (const unsigned int*)(kb + (size_t)bh*NP*16);
  const unsigned int* vg = (const unsigned int*)(vb + (size_t)bh*NP*16);
  int tid = threadIdx.x;
  #pragma unroll
  for(int i = 0; i < K; ++i){
    int hh = gx + D*(sx + i);
    ((uint2*)(kl + i*512))[tid] = ((const uint2*)(kg + hh*512))[tid];
    ((uint2*)(vl + i*512))[tid] = ((const uint2*)(vg + hh*512))[tid];
  }
  __syncthreads();

  int pixoff = tid >> 2, t = tid & 3;
  int y = pixoff;
  int pix = x*64 + y;
  uint2 qd = *(const uint2*)(qb + ((size_t)bh*NP + pix)*16 + 4*t);
  float qx = bflo(qd.x), qy = bfhi(qd.x), qz = bflo(qd.y), qw = bfhi(qd.y);

  int gy = y % D, py = y / D;
  int Lgy = (64 - gy + D - 1) / D;
  int sy = min(max(py - K/2, 0), Lgy - K);

  float sc[K*K];
  #pragma unroll
  for(int i = 0; i < K; ++i){
    #pragma unroll
    for(int j = 0; j < K; ++j){
      int ww = gy + D*(sy + j);
      uint2 kv = *(const uint2*)(kl + i*512 + ww*8 + t*2);
      float s = qx*bflo(kv.x);
      s = fmaf(qy, bfhi(kv.x), s);
      s = fmaf(qz, bflo(kv.y), s);
      s = fmaf(qw, bfhi(kv.y), s);
      sc[i*K + j] = s;
    }
  }
  float mx = -1e30f;
  #pragma unroll
  for(int i = 0; i < K; ++i){
    const float* brow = rpb + (head*RPB + (sx + i - px + (K-1)))*RPB + (sy - py + (K-1));
    #pragma unroll
    for(int j = 0; j < K; ++j){
      float s = sc[i*K + j];
      s += __shfl_xor(s, 1);
      s += __shfl_xor(s, 2);
      s += brow[j];
      sc[i*K + j] = s;
      mx = fmaxf(mx, s);
    }
  }
  float sum = 0.f;
  #pragma unroll
  for(int n = 0; n < K*K; ++n){ float e = __expf(sc[n] - mx); sc[n] = e; sum += e; }
  float rs = 1.0f / sum;
  float4 acc = {0,0,0,0};
  #pragma unroll
  for(int i = 0; i < K; ++i){
    #pragma unroll
    for(int j = 0; j < K; ++j){
      int ww = gy + D*(sy + j);
      float wgt = sc[i*K + j] * rs;
      uint2 vv = *(const uint2*)(vl + i*512 + ww*8 + t*2);
      acc.x = fmaf(wgt, bflo(vv.x), acc.x);
      acc.y = fmaf(wgt, bfhi(vv.x), acc.y);
      acc.z = fmaf(wgt, bflo(vv.y), acc.z);
      acc.w = fmaf(wgt, bfhi(vv.y), acc.w);
    }
  }
  ushort4 o4;
  o4.x = bfr(acc.x); o4.y = bfr(acc.y); o4.z = bfr(acc.z); o4.w = bfr(acc.w);
  *(ushort4*)(outp + ((size_t)(b*NP + pix))*96 + head*16 + 4*t) = o4;
  __syncthreads();
}

// proj GEMM: item = (m_tile, n_half); M=64, N=48; + residual + fused stats
__device__ __forceinline__ void ph_proj(int it,
    const unsigned short* __restrict__ attpm, const unsigned short* __restrict__ wT,
    const float* pb, const float* __restrict__ scx, const float* st,
    const float* m1w, const float* m1b, const float* m2w, const float* m2b,
    float* __restrict__ dst, float* st_out, char* SMc){
  float* T = (float*)SMc;                 // 48*68*4 = 13056
  float* ls = (float*)(SMc + 13312);
  int tid = threadIdx.x;
  int w = tid >> 6, lane = tid & 63, ml = lane & 15, q = lane >> 4;
  int mt = it >> 1, nh = it & 1;
  int m_base = mt*64, n0 = nh*48;
  f32x4 z = {0.f,0.f,0.f,0.f};
  f32x4 acc[3] = {z, z, z};
  const bf16x8* a0 = (const bf16x8*)(attpm + (size_t)(m_base + w*16 + ml)*96 + q*8);
  #pragma unroll
  for(int ks = 0; ks < 3; ++ks){
    bf16x8 av = a0[ks*4];
    #pragma unroll
    for(int g = 0; g < 3; ++g){
      bf16x8 bv = *(const bf16x8*)(wT + (n0 + g*16 + ml)*96 + ks*32 + q*8);
      acc[g] = MFMA16(av, bv, acc[g]);
    }
  }
  #pragma unroll
  for(int g = 0; g < 3; ++g)
    #pragma unroll
    for(int r = 0; r < 4; ++r)
      T[(g*16 + ml)*68 + w*16 + q*4 + r] = acc[g][r];
  __syncthreads();
  int b = m_base >> 12, pxl0 = m_base & 4095;
  float mean, inv, stdv; get_ms(st, b, mean, inv, stdv);
  float s = 0.f, s2 = 0.f;
  for(int idx = tid; idx < 48*64; idx += 256){
    int row = idx >> 6, px = idx & 63;
    int n = n0 + row;
    float rsf = fmaf(m1w[n], stdv, m1b[n]);
    float rbf = fmaf(m2w[n], mean, m2b[n]);
    int ad = (b*CC + n)*NP + pxl0 + px;
    float val = scx[ad] + (T[row*68 + px] + pb[n])*rsf + rbf;
    dst[ad] = val;
    s += val; s2 = fmaf(val, val, s2);
  }
  for(int off = 32; off > 0; off >>= 1){ s += __shfl_down(s, off); s2 += __shfl_down(s2, off); }
  if(lane == 0){ ls[w] = s; ls[4+w] = s2; }
  __syncthreads();
  if(tid == 0){
    atomicAdd(&st_out[b],   ls[0]+ls[1]+ls[2]+ls[3]);
    atomicAdd(&st_out[4+b], ls[4]+ls[5]+ls[6]+ls[7]);
  }
  __syncthreads();
}

// fused LN + mlp1: item = (m_tile, n_half); M=64, N=192 -> relu -> hid
__device__ __forceinline__ void ph_mlp1(int it, const float* __restrict__ xin, const float* st,
    const float* lnw, const float* lnb,
    const unsigned short* __restrict__ wT, const float* b1,
    unsigned short* __restrict__ hid, char* SMc){
  unsigned short* Atl = (unsigned short*)SMc;
  float* scl = (float*)(SMc + 13312);
  float* ofs = (float*)(SMc + 13312 + 384);
  int tid = threadIdx.x;
  int mt = it >> 1, nh = it & 1;
  int m_base = mt*64;
  int b = m_base >> 12, pxl0 = m_base & 4095;
  float mean, inv, stdv; get_ms(st, b, mean, inv, stdv);
  if(tid < 96){ float s = inv*lnw[tid]; scl[tid] = s; ofs[tid] = lnb[tid] - mean*s; }
  __syncthreads();
  const float* src = xin + (size_t)b*CC*NP + pxl0;
  for(int idx = tid; idx < 96*64; idx += 256){
    int c = idx >> 6, p = idx & 63;
    Atl[p*104 + c] = bfr(fmaf(src[c*NP + p], scl[c], ofs[c]));
  }
  __syncthreads();
  int w = tid >> 6, lane = tid & 63, ml = lane & 15, q = lane >> 4;
  const unsigned short* arow = Atl + (w*16 + ml)*104;
  bf16x8 av[3];
  #pragma unroll
  for(int ks = 0; ks < 3; ++ks) av[ks] = *(const bf16x8*)(arow + ks*32 + q*8);
  f32x4 z = {0.f,0.f,0.f,0.f};
  #pragma unroll
  for(int g = 0; g < 4; ++g){
    f32x4 acc[3] = {z, z, z};
    #pragma unroll
    for(int ks = 0; ks < 3; ++ks){
      #pragma unroll
      for(int gg = 0; gg < 3; ++gg){
        bf16x8 bv = *(const bf16x8*)(wT + (nh*192 + g*48 + gg*16 + ml)*96 + ks*32 + q*8);
        acc[gg] = MFMA16(av[ks], bv, acc[gg]);
      }
    }
    #pragma unroll
    for(int gg = 0; gg < 3; ++gg){
      int n = nh*192 + g*48 + gg*16 + ml;
      float bias = b1[n];
      #pragma unroll
      for(int r = 0; r < 4; ++r){
        int m = m_base + w*16 + q*4 + r;
        hid[(size_t)m*384 + n] = bfr(fmaxf(acc[gg][r] + bias, 0.f));
      }
    }
  }
  __syncthreads();
}

// mlp2 (K=384): item = (m_tile, n_half); M=64, N=48; + residual(x1) via st2
__device__ __forceinline__ void ph_mlp2(int it,
    const unsigned short* __restrict__ hid, const unsigned short* __restrict__ wT,
    const float* b2, const float* __restrict__ scx, const float* st,
    const float* m1w, const float* m1b, const float* m2w, const float* m2b,
    float* __restrict__ dst, char* SMc){
  float* T = (float*)SMc;
  int tid = threadIdx.x;
  int w = tid >> 6, lane = tid & 63, ml = lane & 15, q = lane >> 4;
  int mt = it >> 1, nh = it & 1;
  int m_base = mt*64, n0 = nh*48;
  f32x4 z = {0.f,0.f,0.f,0.f};
  f32x4 acc[3] = {z, z, z};
  const bf16x8* a0 = (const bf16x8*)(hid + (size_t)(m_base + w*16 + ml)*384 + q*8);
  #pragma unroll
  for(int ks = 0; ks < 12; ++ks){
    bf16x8 av = a0[ks*4];
    #pragma unroll
    for(int g = 0; g < 3; ++g){
      bf16x8 bv = *(const bf16x8*)(wT + (n0 + g*16 + ml)*384 + ks*32 + q*8);
      acc[g] = MFMA16(av, bv, acc[g]);
    }
  }
  #pragma unroll
  for(int g = 0; g < 3; ++g)
    #pragma unroll
    for(int r = 0; r < 4; ++r)
      T[(g*16 + ml)*68 + w*16 + q*4 + r] = acc[g][r];
  __syncthreads();
  int b = m_base >> 12, pxl0 = m_base & 4095;
  float mean, inv, stdv; get_ms(st, b, mean, inv, stdv);
  for(int idx = tid; idx < 48*64; idx += 256){
    int row = idx >> 6, px = idx & 63;
    int n = n0 + row;
    float rsf = fmaf(m1w[n], stdv, m1b[n]);
    float rbf = fmaf(m2w[n], mean, m2b[n]);
    int ad = (b*CC + n)*NP + pxl0 + px;
    dst[ad] = scx[ad] + (T[row*68 + px] + b2[n])*rsf + rbf;
  }
  __syncthreads();
}

// pixel attention: 4 lanes per pixel, item = 64-px tile
__device__ __forceinline__ void ph_pa(int item, const float* __restrict__ x3,
    const float* bns, const float* __restrict__ w1t, const float* b1,
    const float* w2, const float* b2, float* __restrict__ pa){
  int b = item >> 6;
  int px0 = (item & 63)*64;
  int pxq = threadIdx.x >> 2, t = threadIdx.x & 3;
  int p = px0 + pxq;
  float acc[12];
  #pragma unroll
  for(int h = 0; h < 12; ++h) acc[h] = 0.f;
  #pragma unroll 6
  for(int cc = 0; cc < 24; ++cc){
    int c = t*24 + cc;
    float yv = fmaf(x3[(b*CC + c)*NP + p], bns[c], bns[96 + c]);
    #pragma unroll
    for(int h = 0; h < 12; ++h) acc[h] = fmaf(yv, w1t[c*12 + h], acc[h]);
  }
  #pragma unroll
  for(int h = 0; h < 12; ++h){
    acc[h] += __shfl_xor(acc[h], 1);
    acc[h] += __shfl_xor(acc[h], 2);
  }
  float s = b2[0];
  #pragma unroll
  for(int h = 0; h < 12; ++h) s = fmaf(gelu_f(acc[h] + b1[h]), w2[h], s);
  if(t == 0) pa[b*NP + p] = sigmoid_f(s);
}

__device__ __forceinline__ void ph_gap(int item, const float* __restrict__ x3,
    const float* bns, const float* __restrict__ pa, float* gap, char* SMc){
  float* ls = (float*)SMc;
  int b = item / CC, c = item % CC;
  float scb = bns[c], shb = bns[96 + c];
  float s = 0.f;
  for(int i = threadIdx.x; i < NP; i += 256)
    s = fmaf(fmaf(x3[(b*CC + c)*NP + i], scb, shb), pa[b*NP + i], s);
  for(int off = 32; off > 0; off >>= 1) s += __shfl_down(s, off);
  if((threadIdx.x & 63) == 0) ls[threadIdx.x >> 6] = s;
  __syncthreads();
  if(threadIdx.x == 0) gap[item] = (ls[0]+ls[1]+ls[2]+ls[3]) * (1.0f/4096.0f);
  __syncthreads();
}

__device__ __forceinline__ void ph_ca(int b, const float* gap, const float* w1,
    const float* b1, const float* w2, const float* b2, float* ca, char* SMc){
  float* g = (float*)SMc;
  float* t = g + 96;
  int o = threadIdx.x;
  if(o < 96) g[o] = gap[b*96 + o];
  __syncthreads();
  if(o < 96){
    float a = b1[o];
    for(int c = 0; c < 96; ++c) a = fmaf(g[c], w1[o*96 + c], a);
    t[o] = gelu_f(a);
  }
  __syncthreads();
  if(o < 96){
    float a = b2[o];
    for(int c = 0; c < 96; ++c) a = fmaf(t[c], w2[o*96 + c], a);
    ca[b*96 + o] = sigmoid_f(a);
  }
  __syncthreads();
}

// fused m2a: BN*pa*ca -> GEMM1 -> gelu(LDS) -> GEMM2 -> +x3 -> out; M=64
__device__ __forceinline__ void ph_m2a(int item, const float* __restrict__ x3,
    const float* bns, const float* __restrict__ pa, const float* ca,
    const unsigned short* __restrict__ w1T, const float* b1,
    const unsigned short* __restrict__ w2T, const float* b2,
    const float* __restrict__ scx, float* __restrict__ outp, char* SMc){
  unsigned short* Atl = (unsigned short*)SMc;            // 13312
  unsigned short* tl2 = (unsigned short*)(SMc + 13312);  // 13312
  float* T = (float*)SMc;                                // 96*68*4 = 26112, aliases
  float* scl = (float*)(SMc + 26624);
  float* ofs = (float*)(SMc + 26624 + 384);
  float* pal = (float*)(SMc + 26624 + 768);
  int m_base = item*64;
  int b = m_base >> 12, pxl0 = m_base & 4095;
  int tid = threadIdx.x;
  if(tid < 96){ float cv = ca[b*96 + tid]; scl[tid] = bns[tid]*cv; ofs[tid] = bns[96+tid]*cv; }
  if(tid >= 128 && tid < 192) pal[tid-128] = pa[m_base + (tid-128)];
  __syncthreads();
  const float* src = x3 + (size_t)b*CC*NP + pxl0;
  for(int idx = tid; idx < 96*64; idx += 256){
    int c = idx >> 6, p = idx & 63;
    Atl[p*104 + c] = bfr(fmaf(src[c*NP + p], scl[c], ofs[c]) * pal[p]);
  }
  __syncthreads();
  int w = tid >> 6, lane = tid & 63, ml = lane & 15, q = lane >> 4;
  f32x4 z = {0.f,0.f,0.f,0.f};
  f32x4 acc1[6];
  #pragma unroll
  for(int g=0; g<6; ++g) acc1[g] = z;
  {
    const unsigned short* arow = Atl + (w*16 + ml)*104;
    #pragma unroll
    for(int ks = 0; ks < 3; ++ks){
      bf16x8 av = *(const bf16x8*)(arow + ks*32 + q*8);
      #pragma unroll
      for(int g = 0; g < 6; ++g){
        bf16x8 bv = *(const bf16x8*)(w1T + (g*16 + ml)*96 + ks*32 + q*8);
        acc1[g] = MFMA16(av, bv, acc1[g]);
      }
    }
  }
  #pragma unroll
  for(int g = 0; g < 6; ++g){
    float bias = b1[g*16 + ml];
    #pragma unroll
    for(int r = 0; r < 4; ++r)
      tl2[(w*16 + q*4 + r)*104 + g*16 + ml] = bfr(gelu_f(acc1[g][r] + bias));
  }
  __syncthreads();
  f32x4 acc2[6];
  #pragma unroll
  for(int g=0; g<6; ++g) acc2[g] = z;
  {
    const unsigned short* arow = tl2 + (w*16 + ml)*104;
    #pragma unroll
    for(int ks = 0; ks < 3; ++ks){
      bf16x8 av = *(const bf16x8*)(arow + ks*32 + q*8);
      #pragma unroll
      for(int g = 0; g < 6; ++g){
        bf16x8 bv = *(const bf16x8*)(w2T + (g*16 + ml)*96 + ks*32 + q*8);
        acc2[g] = MFMA16(av, bv, acc2[g]);
      }
    }
  }
  __syncthreads();
  #pragma unroll
  for(int g = 0; g < 6; ++g)
    #pragma unroll
    for(int r = 0; r < 4; ++r)
      T[(g*16 + ml)*68 + w*16 + q*4 + r] = acc2[g][r];
  __syncthreads();
  for(int idx = tid; idx < 96*64; idx += 256){
    int n = idx >> 6, p = idx & 63;
    int ad = (b*CC + n)*NP + pxl0 + p;
    outp[ad] = scx[ad] + T[n*68 + p] + b2[n];
  }
}

// ---- the mega kernel ----
__global__ void __launch_bounds__(256, 4) mega_kernel(
    const float* x, const float* lnw, const float* lnb,
    const float* m1w, const float* m1b, const float* m2w, const float* m2b,
    const float* qkv1w, const float* qkv1b, const float* proj1w, const float* proj1b,
    const float* rpb1,
    const float* qkv2w, const float* qkv2b, const float* proj2w, const float* proj2b,
    const float* rpb2,
    const float* mw1, const float* mb1, const float* mw2, const float* mb2,
    const float* bng, const float* bnb, const float* bnm, const float* bnv,
    const float* paw1, const float* pab1, const float* paw2, const float* pab2,
    const float* caw1, const float* cab1, const float* caw2, const float* cab2,
    const float* aw1, const float* ab1, const float* aw2, const float* ab2,
    float* ws, float* out){
  __shared__ __align__(16) char SM[28672];
  unsigned int* bar = (unsigned int*)(ws + 32);
  float* st0 = ws;
  float* st1 = ws + 8;
  float* st2 = ws + 16;
  unsigned short* q     = (unsigned short*)(ws + WS_Q);
  unsigned short* k     = (unsigned short*)(ws + WS_K);
  unsigned short* v     = (unsigned short*)(ws + WS_V);
  unsigned short* attpm = (unsigned short*)(ws + WS_ATTPM);
  unsigned short* hid   = (unsigned short*)(ws + WS_Q);
  float* x1  = ws + WS_X1;
  float* x2  = ws + WS_X2;
  float* x3  = ws + WS_X3;
  float* pab = ws + WS_PA;
  float* gpb = ws + WS_GAP;
  float* cab = ws + WS_CA;
  float* bns = ws + WBNS;
  const unsigned short* wqkv1 = (const unsigned short*)(ws + WQKV1);
  const unsigned short* wqkv2 = (const unsigned short*)(ws + WQKV2);
  const unsigned short* wproj1 = (const unsigned short*)(ws + WPROJ1);
  const unsigned short* wproj2 = (const unsigned short*)(ws + WPROJ2);
  const unsigned short* wmlp1 = (const unsigned short*)(ws + WMLP1);
  const unsigned short* wmlp2 = (const unsigned short*)(ws + WMLP2);
  const unsigned short* wm2a1 = (const unsigned short*)(ws + WM2A1);
  const unsigned short* wm2a2 = (const unsigned short*)(ws + WM2A2);
  const float* wpa1t = ws + WPA1T;
  int blk = blockIdx.x;

  // phase 0: weight prep + stats(x)
  ph_prep(blk*256 + threadIdx.x, qkv1w, qkv2w, proj1w, proj2w, mw1, mw2, aw1, aw2,
          paw1, bng, bnb, bnm, bnv, ws);
  if(blk < 384) ph_stats(blk, x, st0, SM);
  gbar(bar, 1);
  // stage 1
  if(blk < 512) ph_qkv(blk, x, st0, lnw, lnb, wqkv1, qkv1b, q, k, v, SM);
  gbar(bar, 2);
  for(int it = blk; it < 1536; it += (int)NB)
    ph_attn<7,1,13>(it, q, k, v, rpb1, attpm, SM);
  gbar(bar, 3);
  if(blk < 512) ph_proj(blk, attpm, wproj1, proj1b, x, st0, m1w, m1b, m2w, m2b, x1, st1, SM);
  gbar(bar, 4);
  // stage 2
  if(blk < 512) ph_qkv(blk, x1, st1, lnw, lnb, wqkv2, qkv2b, q, k, v, SM);
  gbar(bar, 5);
  for(int it = blk; it < 1536; it += (int)NB)
    ph_attn<5,8,9>(it, q, k, v, rpb2, attpm, SM);
  gbar(bar, 6);
  if(blk < 512) ph_proj(blk, attpm, wproj2, proj2b, x1, st1, m1w, m1b, m2w, m2b, x2, st2, SM);
  gbar(bar, 7);
  // stage 3 (sc = x1)
  if(blk < 512) ph_mlp1(blk, x2, st2, lnw, lnb, wmlp1, mb1, hid, SM);
  gbar(bar, 8);
  if(blk < 512) ph_mlp2(blk, hid, wmlp2, mb2, x1, st2, m1w, m1b, m2w, m2b, x3, SM);
  gbar(bar, 9);
  // stage 4 (sc = x3)
  if(blk < 256) ph_pa(blk, x3, bns, wpa1t, pab1, paw2, pab2, pab);
  gbar(bar, 10);
  if(blk < 384) ph_gap(blk, x3, bns, pab, gpb, SM);
  gbar(bar, 11);
  if(blk < 4) ph_ca(blk, gpb, caw1, cab1, caw2, cab2, cab, SM);
  gbar(bar, 12);
  if(blk < 256) ph_m2a(blk, x3, bns, pab, cab, wm2a1, ab1, wm2a2, ab2, x3, out, SM);
}

extern "C" void kernel_launch(void* const* d_in, const int* in_sizes, int n_in,
                              void* d_out, int out_size, void* d_ws, size_t ws_size,
                              hipStream_t stream){
  (void)in_sizes; (void)n_in; (void)out_size; (void)ws_size;
  float* ws  = (float*)d_ws;
  float* out = (float*)d_out;
  hipMemsetAsync(d_ws, 0, 64*sizeof(float), stream);
  mega_kernel<<<(int)NB, 256, 0, stream>>>(
      (const float*)d_in[0],  (const float*)d_in[1],  (const float*)d_in[2],
      (const float*)d_in[3],  (const float*)d_in[4],  (const float*)d_in[5],
      (const float*)d_in[6],  (const float*)d_in[7],  (const float*)d_in[8],
      (const float*)d_in[9],  (const float*)d_in[10], (const float*)d_in[11],
      (const float*)d_in[12], (const float*)d_in[13], (const float*)d_in[14],
      (const float*)d_in[15], (const float*)d_in[16], (const float*)d_in[17],
      (const float*)d_in[18], (const float*)d_in[19], (const float*)d_in[20],
      (const float*)d_in[21], (const float*)d_in[22], (const float*)d_in[23],
      (const float*)d_in[24], (const float*)d_in[25], (const float*)d_in[26],
      (const float*)d_in[27], (const float*)d_in[28], (const float*)d_in[29],
      (const float*)d_in[30], (const float*)d_in[31], (const float*)d_in[32],
      (const float*)d_in[33], (const float*)d_in[34], (const float*)d_in[35],
      (const float*)d_in[36], ws, out);
}

// Round 10
// 300.644 us; speedup vs baseline: 10.2449x; 10.2449x over previous
//
#include <hip/hip_runtime.h>
#include <math.h>

#define CC 96
#define NP 4096
#define NHEADS 6
#define NELEMF 393216.0f
#define EPSF 1e-5f

typedef __attribute__((ext_vector_type(8))) short bf16x8;
typedef __attribute__((ext_vector_type(4))) float f32x4;
#define MFMA16(a,b,c) __builtin_amdgcn_mfma_f32_16x16x32_bf16(a,b,c,0,0,0)

// ---- workspace layout (float offsets) ----
#define WQKV1  64
#define WQKV2  (WQKV1+13824)
#define WPROJ1 (WQKV2+13824)
#define WPROJ2 (WPROJ1+4608)
#define WMLP1  (WPROJ2+4608)
#define WMLP2  (WMLP1+18432)
#define WM2A1  (WMLP2+18432)
#define WM2A2  (WM2A1+4608)
#define WPA1T  (WM2A2+4608)
#define WBNS   (WPA1T+1152)
#define WS_Q   870784
#define WS_K   (WS_Q+786432)
#define WS_V   (WS_K+786432)
#define WS_ATTPM (WS_V+786432)
#define WS_X1  (WS_ATTPM+786432)  // hid (bf16 16384x384) reuses WS_Q..WS_X1
#define WS_X2  (WS_X1+1572864)
#define WS_X3  (WS_X2+1572864)
#define WS_PA  (WS_X3+1572864)
#define WS_GAP (WS_PA+16384)
#define WS_CA  (WS_GAP+384)

__device__ __forceinline__ float gelu_f(float x){
  return 0.5f * x * (1.0f + erff(x * 0.7071067811865476f));
}
__device__ __forceinline__ float sigmoid_f(float x){
  return 1.0f / (1.0f + __expf(-x));
}
__device__ __forceinline__ unsigned short bfr(float f){
  unsigned int u = __float_as_uint(f);
  u += 0x7fffu + ((u >> 16) & 1u);
  return (unsigned short)(u >> 16);
}
__device__ __forceinline__ float bflo(unsigned int u){ return __uint_as_float(u << 16); }
__device__ __forceinline__ float bfhi(unsigned int u){ return __uint_as_float(u & 0xffff0000u); }
__device__ __forceinline__ void get_ms(const float* st, int b, float& mean, float& inv, float& stdv){
  float s = st[b], s2 = st[4+b];
  mean = s * (1.0f/NELEMF);
  float var = fmaxf(s2 * (1.0f/NELEMF) - mean*mean, 0.0f);
  stdv = sqrtf(var + EPSF);
  inv = 1.0f / stdv;
}

// ---- combined: stats(x) for blocks <384, weight prep for blocks >=384 ----
__global__ void prep_stats_kernel(const float* __restrict__ x, float* __restrict__ st,
                             const float* __restrict__ q1, const float* __restrict__ q2,
                             const float* __restrict__ p1, const float* __restrict__ p2,
                             const float* __restrict__ w1, const float* __restrict__ w2,
                             const float* __restrict__ a1, const float* __restrict__ a2,
                             const float* __restrict__ pw1,
                             const float* __restrict__ bg, const float* __restrict__ bb,
                             const float* __restrict__ bm, const float* __restrict__ bv,
                             float* __restrict__ ws){
  if(blockIdx.x < 384){
    int b = blockIdx.x / CC, c = blockIdx.x % CC;
    const float* p = x + (b*CC + c)*NP;
    float s = 0.f, s2 = 0.f;
    for(int i = threadIdx.x; i < NP; i += 256){ float v = p[i]; s += v; s2 = fmaf(v, v, s2); }
    for(int off = 32; off > 0; off >>= 1){ s += __shfl_down(s, off); s2 += __shfl_down(s2, off); }
    __shared__ float ls[8];
    int wid = threadIdx.x >> 6;
    if((threadIdx.x & 63) == 0){ ls[wid] = s; ls[4+wid] = s2; }
    __syncthreads();
    if(threadIdx.x == 0){
      atomicAdd(&st[b],   ls[0]+ls[1]+ls[2]+ls[3]);
      atomicAdd(&st[4+b], ls[4]+ls[5]+ls[6]+ls[7]);
    }
    return;
  }
  int gid = (blockIdx.x - 384)*256 + threadIdx.x;
  if(gid < 27648){ int n = gid/96, c = gid%96; ((unsigned short*)(ws+WQKV1))[gid] = bfr(q1[c*288+n]); }
  else if(gid < 55296){ int g = gid-27648; int n = g/96, c = g%96; ((unsigned short*)(ws+WQKV2))[g] = bfr(q2[c*288+n]); }
  else if(gid < 64512){ int g = gid-55296; int n = g/96, c = g%96; ((unsigned short*)(ws+WPROJ1))[g] = bfr(p1[c*96+n]); }
  else if(gid < 73728){ int g = gid-64512; int n = g/96, c = g%96; ((unsigned short*)(ws+WPROJ2))[g] = bfr(p2[c*96+n]); }
  else if(gid < 110592){ int g = gid-73728; ((unsigned short*)(ws+WMLP1))[g] = bfr(w1[g]); }
  else if(gid < 147456){ int g = gid-110592; ((unsigned short*)(ws+WMLP2))[g] = bfr(w2[g]); }
  else if(gid < 156672){ int g = gid-147456; ((unsigned short*)(ws+WM2A1))[g] = bfr(a1[g]); }
  else if(gid < 165888){ int g = gid-156672; ((unsigned short*)(ws+WM2A2))[g] = bfr(a2[g]); }
  else if(gid < 167040){ int g = gid-165888; int c = g/12, h = g%12; ws[WPA1T + g] = pw1[h*96+c]; }
  else if(gid < 167136){ int c = gid-167040;
    float sc = rsqrtf(bv[c] + EPSF) * bg[c];
    ws[WBNS + c] = sc;
    ws[WBNS + 96 + c] = bb[c] - bm[c]*sc;
  }
}

// ---- fused LN + QKV GEMM: M=64, N=144 per block (blockIdx.y = n-half) ----
__global__ void __launch_bounds__(256) gemm_qkv_kernel(
    const float* __restrict__ xin, const float* __restrict__ st,
    const float* __restrict__ lnw, const float* __restrict__ lnb,
    const unsigned short* __restrict__ wT, const float* __restrict__ qb,
    unsigned short* __restrict__ qo, unsigned short* __restrict__ ko, unsigned short* __restrict__ vo){
  __shared__ unsigned short Atl[64*104];
  __shared__ float scl[96], ofs[96];
  int m_base = blockIdx.x*64;
  int nh = blockIdx.y;
  int b = m_base >> 12, pxl0 = m_base & 4095;
  float mean, inv, stdv; get_ms(st, b, mean, inv, stdv);
  int tid = threadIdx.x;
  if(tid < 96){ float s = inv*lnw[tid]; scl[tid] = s; ofs[tid] = lnb[tid] - mean*s; }
  __syncthreads();
  const float* src = xin + (size_t)b*CC*NP + pxl0;
  for(int idx = tid; idx < 96*64; idx += 256){
    int c = idx >> 6, p = idx & 63;
    Atl[p*104 + c] = bfr(fmaf(src[c*NP + p], scl[c], ofs[c]));
  }
  __syncthreads();
  int w = tid >> 6, lane = tid & 63, ml = lane & 15, q = lane >> 4;
  const unsigned short* arow = Atl + (w*16 + ml)*104;
  bf16x8 av[3];
  #pragma unroll
  for(int ks = 0; ks < 3; ++ks) av[ks] = *(const bf16x8*)(arow + ks*32 + q*8);
  f32x4 z = {0.f,0.f,0.f,0.f};
  #pragma unroll
  for(int g = 0; g < 3; ++g){
    f32x4 acc[3] = {z, z, z};
    #pragma unroll
    for(int ks = 0; ks < 3; ++ks){
      #pragma unroll
      for(int gg = 0; gg < 3; ++gg){
        bf16x8 bv = *(const bf16x8*)(wT + (nh*144 + g*48 + gg*16 + ml)*96 + ks*32 + q*8);
        acc[gg] = MFMA16(av[ks], bv, acc[gg]);
      }
    }
    #pragma unroll
    for(int gg = 0; gg < 3; ++gg){
      int nfb = nh*144 + g*48 + gg*16;
      int t = nfb/96, head = (nfb%96) >> 4;
      float scale = (t == 0) ? 0.25f : 1.0f;
      unsigned short* dst = (t == 0) ? qo : (t == 1) ? ko : vo;
      float bias = qb[nfb + ml];
      #pragma unroll
      for(int r = 0; r < 4; ++r){
        int pxl = pxl0 + w*16 + q*4 + r;
        dst[(((size_t)(b*NHEADS + head))*NP + pxl)*16 + ml] = bfr((acc[gg][r] + bias)*scale);
      }
    }
  }
}

// ---- proj GEMM: attpm @ projT -> c-major + residual + fused stats (M=128) ----
__global__ void __launch_bounds__(256) gemm_proj_kernel(
    const unsigned short* __restrict__ attpm, const unsigned short* __restrict__ wT,
    const float* __restrict__ pb, const float* __restrict__ scx, const float* __restrict__ st,
    const float* __restrict__ m1w, const float* __restrict__ m1b,
    const float* __restrict__ m2w, const float* __restrict__ m2b,
    float* __restrict__ dst, float* __restrict__ st_out){
  int w = threadIdx.x >> 6, lane = threadIdx.x & 63;
  int ml = lane & 15, q = lane >> 4;
  int m_base = blockIdx.x*128 + w*32;
  int n0 = blockIdx.y*48;
  f32x4 acc[2][3];
  f32x4 z = {0.f,0.f,0.f,0.f};
  #pragma unroll
  for(int f=0; f<2; ++f) for(int g=0; g<3; ++g) acc[f][g] = z;
  {
    const bf16x8* a0 = (const bf16x8*)(attpm + (size_t)(m_base + ml)*96 + q*8);
    const bf16x8* a1 = (const bf16x8*)(attpm + (size_t)(m_base + 16 + ml)*96 + q*8);
    #pragma unroll
    for(int ks = 0; ks < 3; ++ks){
      bf16x8 av0 = a0[ks*4], av1 = a1[ks*4];
      #pragma unroll
      for(int g = 0; g < 3; ++g){
        bf16x8 bv = *(const bf16x8*)(wT + (n0 + g*16 + ml)*96 + ks*32 + q*8);
        acc[0][g] = MFMA16(av0, bv, acc[0][g]);
        acc[1][g] = MFMA16(av1, bv, acc[1][g]);
      }
    }
  }
  __shared__ float T[48*133];
  #pragma unroll
  for(int f = 0; f < 2; ++f)
    #pragma unroll
    for(int g = 0; g < 3; ++g)
      #pragma unroll
      for(int r = 0; r < 4; ++r)
        T[(g*16 + ml)*133 + w*32 + f*16 + q*4 + r] = acc[f][g][r];
  __syncthreads();
  int b = (blockIdx.x*128) >> 12, pxl0 = (blockIdx.x*128) & 4095;
  float mean, inv, stdv; get_ms(st, b, mean, inv, stdv);
  float s = 0.f, s2 = 0.f;
  for(int idx = threadIdx.x; idx < 48*128; idx += 256){
    int row = idx >> 7, px = idx & 127;
    int n = n0 + row;
    float rsf = fmaf(m1w[n], stdv, m1b[n]);
    float rbf = fmaf(m2w[n], mean, m2b[n]);
    int ad = (b*CC + n)*NP + pxl0 + px;
    float val = scx[ad] + (T[row*133 + px] + pb[n])*rsf + rbf;
    dst[ad] = val;
    s += val; s2 = fmaf(val, val, s2);
  }
  for(int off = 32; off > 0; off >>= 1){ s += __shfl_down(s, off); s2 += __shfl_down(s2, off); }
  __shared__ float ls[8];
  int wid = threadIdx.x >> 6;
  if((threadIdx.x & 63) == 0){ ls[wid] = s; ls[4+wid] = s2; }
  __syncthreads();
  if(threadIdx.x == 0){
    atomicAdd(&st_out[b],   ls[0]+ls[1]+ls[2]+ls[3]);
    atomicAdd(&st_out[4+b], ls[4]+ls[5]+ls[6]+ls[7]);
  }
}

// ---- fused LN + mlp1 GEMM: M=64, N=192 per block (blockIdx.y = n-half) ----
__global__ void __launch_bounds__(256) gemm_mlp1_kernel(
    const float* __restrict__ xin, const float* __restrict__ st,
    const float* __restrict__ lnw, const float* __restrict__ lnb,
    const unsigned short* __restrict__ wT, const float* __restrict__ b1,
    unsigned short* __restrict__ hid){
  __shared__ unsigned short Atl[64*104];
  __shared__ float scl[96], ofs[96];
  int m_base = blockIdx.x*64;
  int nh = blockIdx.y;
  int b = m_base >> 12, pxl0 = m_base & 4095;
  float mean, inv, stdv; get_ms(st, b, mean, inv, stdv);
  int tid = threadIdx.x;
  if(tid < 96){ float s = inv*lnw[tid]; scl[tid] = s; ofs[tid] = lnb[tid] - mean*s; }
  __syncthreads();
  const float* src = xin + (size_t)b*CC*NP + pxl0;
  for(int idx = tid; idx < 96*64; idx += 256){
    int c = idx >> 6, p = idx & 63;
    Atl[p*104 + c] = bfr(fmaf(src[c*NP + p], scl[c], ofs[c]));
  }
  __syncthreads();
  int w = tid >> 6, lane = tid & 63, ml = lane & 15, q = lane >> 4;
  const unsigned short* arow = Atl + (w*16 + ml)*104;
  bf16x8 av[3];
  #pragma unroll
  for(int ks = 0; ks < 3; ++ks) av[ks] = *(const bf16x8*)(arow + ks*32 + q*8);
  f32x4 z = {0.f,0.f,0.f,0.f};
  #pragma unroll
  for(int g = 0; g < 4; ++g){
    f32x4 acc[3] = {z, z, z};
    #pragma unroll
    for(int ks = 0; ks < 3; ++ks){
      #pragma unroll
      for(int gg = 0; gg < 3; ++gg){
        bf16x8 bv = *(const bf16x8*)(wT + (nh*192 + g*48 + gg*16 + ml)*96 + ks*32 + q*8);
        acc[gg] = MFMA16(av[ks], bv, acc[gg]);
      }
    }
    #pragma unroll
    for(int gg = 0; gg < 3; ++gg){
      int n = nh*192 + g*48 + gg*16 + ml;
      float bias = b1[n];
      #pragma unroll
      for(int r = 0; r < 4; ++r){
        int m = m_base + w*16 + q*4 + r;
        hid[(size_t)m*384 + n] = bfr(fmaxf(acc[gg][r] + bias, 0.f));
      }
    }
  }
}

// ---- mlp2 GEMM (K=384): hid @ mlp2T -> c-major + residual(x1) via st2 ----
__global__ void __launch_bounds__(256) gemm_mlp2_kernel(
    const unsigned short* __restrict__ hid, const unsigned short* __restrict__ wT,
    const float* __restrict__ b2, const float* __restrict__ scx, const float* __restrict__ st,
    const float* __restrict__ m1w, const float* __restrict__ m1b,
    const float* __restrict__ m2w, const float* __restrict__ m2b,
    float* __restrict__ dst){
  int w = threadIdx.x >> 6, lane = threadIdx.x & 63;
  int ml = lane & 15, q = lane >> 4;
  int m_base = blockIdx.x*128 + w*32;
  int n0 = blockIdx.y*48;
  f32x4 acc[2][3];
  f32x4 z = {0.f,0.f,0.f,0.f};
  #pragma unroll
  for(int f=0; f<2; ++f) for(int g=0; g<3; ++g) acc[f][g] = z;
  {
    const bf16x8* a0 = (const bf16x8*)(hid + (size_t)(m_base + ml)*384 + q*8);
    const bf16x8* a1 = (const bf16x8*)(hid + (size_t)(m_base + 16 + ml)*384 + q*8);
    #pragma unroll
    for(int ks = 0; ks < 12; ++ks){
      bf16x8 av0 = a0[ks*4], av1 = a1[ks*4];
      #pragma unroll
      for(int g = 0; g < 3; ++g){
        bf16x8 bv = *(const bf16x8*)(wT + (n0 + g*16 + ml)*384 + ks*32 + q*8);
        acc[0][g] = MFMA16(av0, bv, acc[0][g]);
        acc[1][g] = MFMA16(av1, bv, acc[1][g]);
      }
    }
  }
  __shared__ float T[48*133];
  #pragma unroll
  for(int f = 0; f < 2; ++f)
    #pragma unroll
    for(int g = 0; g < 3; ++g)
      #pragma unroll
      for(int r = 0; r < 4; ++r)
        T[(g*16 + ml)*133 + w*32 + f*16 + q*4 + r] = acc[f][g][r];
  __syncthreads();
  int b = (blockIdx.x*128) >> 12, pxl0 = (blockIdx.x*128) & 4095;
  float mean, inv, stdv; get_ms(st, b, mean, inv, stdv);
  for(int idx = threadIdx.x; idx < 48*128; idx += 256){
    int row = idx >> 7, px = idx & 127;
    int n = n0 + row;
    float rsf = fmaf(m1w[n], stdv, m1b[n]);
    float rbf = fmaf(m2w[n], mean, m2b[n]);
    int ad = (b*CC + n)*NP + pxl0 + px;
    dst[ad] = scx[ad] + (T[row*133 + px] + b2[n])*rsf + rbf;
  }
}

// ---- fused m2a: BN*pa*ca load -> GEMM1 -> gelu(LDS) -> GEMM2 -> +x3 -> out (M=64) ----
__global__ void __launch_bounds__(256) gemm_m2a_kernel(
    const float* __restrict__ x3, const float* __restrict__ bns,
    const float* __restrict__ pa, const float* __restrict__ ca,
    const unsigned short* __restrict__ w1T, const float* __restrict__ b1,
    const unsigned short* __restrict__ w2T, const float* __restrict__ b2,
    const float* __restrict__ scx, float* __restrict__ outp){
  __shared__ __align__(16) char smbuf[26624];
  __shared__ float scl[96], ofs[96], pal[64];
  unsigned short* Atl = (unsigned short*)smbuf;
  unsigned short* tl2 = (unsigned short*)(smbuf + 13312);
  float* T = (float*)smbuf;
  int m_base = blockIdx.x*64;
  int b = m_base >> 12, pxl0 = m_base & 4095;
  int tid = threadIdx.x;
  if(tid < 96){ float cv = ca[b*96 + tid]; scl[tid] = bns[tid]*cv; ofs[tid] = bns[96+tid]*cv; }
  if(tid >= 128 && tid < 192) pal[tid-128] = pa[m_base + (tid-128)];
  __syncthreads();
  const float* src = x3 + (size_t)b*CC*NP + pxl0;
  for(int idx = tid; idx < 96*64; idx += 256){
    int c = idx >> 6, p = idx & 63;
    Atl[p*104 + c] = bfr(fmaf(src[c*NP + p], scl[c], ofs[c]) * pal[p]);
  }
  __syncthreads();
  int w = tid >> 6, lane = tid & 63, ml = lane & 15, q = lane >> 4;
  f32x4 z = {0.f,0.f,0.f,0.f};
  f32x4 acc1[6];
  #pragma unroll
  for(int g=0; g<6; ++g) acc1[g] = z;
  {
    const unsigned short* arow = Atl + (w*16 + ml)*104;
    #pragma unroll
    for(int ks = 0; ks < 3; ++ks){
      bf16x8 av = *(const bf16x8*)(arow + ks*32 + q*8);
      #pragma unroll
      for(int g = 0; g < 6; ++g){
        bf16x8 bv = *(const bf16x8*)(w1T + (g*16 + ml)*96 + ks*32 + q*8);
        acc1[g] = MFMA16(av, bv, acc1[g]);
      }
    }
  }
  #pragma unroll
  for(int g = 0; g < 6; ++g){
    float bias = b1[g*16 + ml];
    #pragma unroll
    for(int r = 0; r < 4; ++r)
      tl2[(w*16 + q*4 + r)*104 + g*16 + ml] = bfr(gelu_f(acc1[g][r] + bias));
  }
  __syncthreads();
  f32x4 acc2[6];
  #pragma unroll
  for(int g=0; g<6; ++g) acc2[g] = z;
  {
    const unsigned short* arow = tl2 + (w*16 + ml)*104;
    #pragma unroll
    for(int ks = 0; ks < 3; ++ks){
      bf16x8 av = *(const bf16x8*)(arow + ks*32 + q*8);
      #pragma unroll
      for(int g = 0; g < 6; ++g){
        bf16x8 bv = *(const bf16x8*)(w2T + (g*16 + ml)*96 + ks*32 + q*8);
        acc2[g] = MFMA16(av, bv, acc2[g]);
      }
    }
  }
  __syncthreads();
  #pragma unroll
  for(int g = 0; g < 6; ++g)
    #pragma unroll
    for(int r = 0; r < 4; ++r)
      T[(g*16 + ml)*68 + w*16 + q*4 + r] = acc2[g][r];
  __syncthreads();
  for(int idx = tid; idx < 96*64; idx += 256){
    int n = idx >> 6, p = idx & 63;
    int ad = (b*CC + n)*NP + pxl0 + p;
    outp[ad] = scx[ad] + T[n*68 + p] + b2[n];
  }
}

// ---- neighborhood attention: bf16 LDS-staged k/v, output pixel-major bf16 ----
template<int K, int D, int RPB>
__global__ void __launch_bounds__(256) attn_kernel(
    const unsigned short* __restrict__ qb, const unsigned short* __restrict__ kb,
    const unsigned short* __restrict__ vb, const float* __restrict__ rpb,
    unsigned short* __restrict__ outp){
  int bh = blockIdx.x >> 6;
  int x = blockIdx.x & 63;
  int head = bh % NHEADS, b = bh / NHEADS;

  int gx = x % D, px = x / D;
  int Lgx = (64 - gx + D - 1) / D;
  int sx = min(max(px - K/2, 0), Lgx - K);

  __shared__ unsigned int sm[2*K*512];
  unsigned int* kl = sm;
  unsigned int* vl = sm + K*512;
  const unsigned int* kg = (const unsigned int*)(kb + (size_t)bh*NP*16);
  const unsigned int* vg = (const unsigned int*)(vb + (size_t)bh*NP*16);
  int tid = threadIdx.x;
  #pragma unroll
  for(int i = 0; i < K; ++i){
    int hh = gx + D*(sx + i);
    ((uint2*)(kl + i*512))[tid] = ((const uint2*)(kg + hh*512))[tid];
    ((uint2*)(vl + i*512))[tid] = ((const uint2*)(vg + hh*512))[tid];
  }
  __syncthreads();

  int pixoff = tid >> 2, t = tid & 3;
  int y = pixoff;
  int pix = x*64 + y;
  uint2 qd = *(const uint2*)(qb + ((size_t)bh*NP + pix)*16 + 4*t);
  float qx = bflo(qd.x), qy = bfhi(qd.x), qz = bflo(qd.y), qw = bfhi(qd.y);

  int gy = y % D, py = y / D;
  int Lgy = (64 - gy + D - 1) / D;
  int sy = min(max(py - K/2, 0), Lgy - K);

  float sc[K*K];
  #pragma unroll
  for(int i = 0; i < K; ++i){
    #pragma unroll
    for(int j = 0; j < K; ++j){
      int ww = gy + D*(sy + j);
      uint2 kv = *(const uint2*)(kl + i*512 + ww*8 + t*2);
      float s = qx*bflo(kv.x);
      s = fmaf(qy, bfhi(kv.x), s);
      s = fmaf(qz, bflo(kv.y), s);
      s = fmaf(qw, bfhi(kv.y), s);
      sc[i*K + j] = s;
    }
  }
  float mx = -1e30f;
  #pragma unroll
  for(int i = 0; i < K; ++i){
    const float* brow = rpb + (head*RPB + (sx + i - px + (K-1)))*RPB + (sy - py + (K-1));
    #pragma unroll
    for(int j = 0; j < K; ++j){
      float s = sc[i*K + j];
      s += __shfl_xor(s, 1);
      s += __shfl_xor(s, 2);
      s += brow[j];
      sc[i*K + j] = s;
      mx = fmaxf(mx, s);
    }
  }
  float sum = 0.f;
  #pragma unroll
  for(int n = 0; n < K*K; ++n){ float e = __expf(sc[n] - mx); sc[n] = e; sum += e; }
  float rs = 1.0f / sum;
  float4 acc = {0,0,0,0};
  #pragma unroll
  for(int i = 0; i < K; ++i){
    #pragma unroll
    for(int j = 0; j < K; ++j){
      int ww = gy + D*(sy + j);
      float wgt = sc[i*K + j] * rs;
      uint2 vv = *(const uint2*)(vl + i*512 + ww*8 + t*2);
      acc.x = fmaf(wgt, bflo(vv.x), acc.x);
      acc.y = fmaf(wgt, bfhi(vv.x), acc.y);
      acc.z = fmaf(wgt, bflo(vv.y), acc.z);
      acc.w = fmaf(wgt, bfhi(vv.y), acc.w);
    }
  }
  ushort4 o4;
  o4.x = bfr(acc.x); o4.y = bfr(acc.y); o4.z = bfr(acc.z); o4.w = bfr(acc.w);
  *(ushort4*)(outp + ((size_t)(b*NP + pix))*96 + head*16 + 4*t) = o4;
}

// ---- pixel attention: 4 lanes per pixel (lane owns 24 channels), 256 blocks ----
__global__ void __launch_bounds__(256) pa_kernel(
    const float* __restrict__ x3, const float* __restrict__ bns,
    const float* __restrict__ w1t, const float* __restrict__ b1,
    const float* __restrict__ w2, const float* __restrict__ b2,
    float* __restrict__ pa){
  int b = blockIdx.x >> 6;
  int px0 = (blockIdx.x & 63)*64;
  int pxq = threadIdx.x >> 2, t = threadIdx.x & 3;
  int p = px0 + pxq;
  float acc[12];
  #pragma unroll
  for(int h = 0; h < 12; ++h) acc[h] = 0.f;
  #pragma unroll 6
  for(int cc = 0; cc < 24; ++cc){
    int c = t*24 + cc;
    float yv = fmaf(x3[(b*CC + c)*NP + p], bns[c], bns[96 + c]);
    #pragma unroll
    for(int h = 0; h < 12; ++h) acc[h] = fmaf(yv, w1t[c*12 + h], acc[h]);
  }
  #pragma unroll
  for(int h = 0; h < 12; ++h){
    acc[h] += __shfl_xor(acc[h], 1);
    acc[h] += __shfl_xor(acc[h], 2);
  }
  float s = b2[0];
  #pragma unroll
  for(int h = 0; h < 12; ++h) s = fmaf(gelu_f(acc[h] + b1[h]), w2[h], s);
  if(t == 0) pa[b*NP + p] = sigmoid_f(s);
}

// ---- global average pool of pa*BN(x3): one block per (b,c), direct write ----
__global__ void gap_kernel(const float* __restrict__ x3, const float* __restrict__ bns,
                           const float* __restrict__ pa, float* __restrict__ gap){
  int b = blockIdx.x / CC, c = blockIdx.x % CC;
  float scb = bns[c], shb = bns[96 + c];
  float s = 0.f;
  for(int i = threadIdx.x; i < NP; i += 256)
    s = fmaf(fmaf(x3[(b*CC + c)*NP + i], scb, shb), pa[b*NP + i], s);
  for(int off = 32; off > 0; off >>= 1) s += __shfl_down(s, off);
  __shared__ float ls[4];
  if((threadIdx.x & 63) == 0) ls[threadIdx.x >> 6] = s;
  __syncthreads();
  if(threadIdx.x == 0) gap[blockIdx.x] = (ls[0]+ls[1]+ls[2]+ls[3]) * (1.0f/4096.0f);
}

// ---- channel attention ----
__global__ void ca_kernel(const float* __restrict__ gap, const float* __restrict__ w1,
                          const float* __restrict__ b1, const float* __restrict__ w2,
                          const float* __restrict__ b2, float* __restrict__ ca){
  int b = blockIdx.x; int o = threadIdx.x;
  __shared__ float g[96], t[96];
  if(o < 96) g[o] = gap[b*96 + o];
  __syncthreads();
  if(o < 96){
    float a = b1[o];
    for(int c = 0; c < 96; ++c) a = fmaf(g[c], w1[o*96 + c], a);
    t[o] = gelu_f(a);
  }
  __syncthreads();
  if(o < 96){
    float a = b2[o];
    for(int c = 0; c < 96; ++c) a = fmaf(t[c], w2[o*96 + c], a);
    ca[b*96 + o] = sigmoid_f(a);
  }
}

extern "C" void kernel_launch(void* const* d_in, const int* in_sizes, int n_in,
                              void* d_out, int out_size, void* d_ws, size_t ws_size,
                              hipStream_t stream){
  (void)in_sizes; (void)n_in; (void)out_size; (void)ws_size;
  const float* x     = (const float*)d_in[0];
  const float* lnw   = (const float*)d_in[1];
  const float* lnb   = (const float*)d_in[2];
  const float* m1w   = (const float*)d_in[3];
  const float* m1b   = (const float*)d_in[4];
  const float* m2w   = (const float*)d_in[5];
  const float* m2b   = (const float*)d_in[6];
  const float* qkv1w = (const float*)d_in[7];
  const float* qkv1b = (const float*)d_in[8];
  const float* proj1w= (const float*)d_in[9];
  const float* proj1b= (const float*)d_in[10];
  const float* rpb1  = (const float*)d_in[11];
  const float* qkv2w = (const float*)d_in[12];
  const float* qkv2b = (const float*)d_in[13];
  const float* proj2w= (const float*)d_in[14];
  const float* proj2b= (const float*)d_in[15];
  const float* rpb2  = (const float*)d_in[16];
  const float* mw1   = (const float*)d_in[17];
  const float* mb1   = (const float*)d_in[18];
  const float* mw2   = (const float*)d_in[19];
  const float* mb2   = (const float*)d_in[20];
  const float* bng   = (const float*)d_in[21];
  const float* bnb   = (const float*)d_in[22];
  const float* bnm   = (const float*)d_in[23];
  const float* bnv   = (const float*)d_in[24];
  const float* paw1  = (const float*)d_in[25];
  const float* pab1  = (const float*)d_in[26];
  const float* paw2  = (const float*)d_in[27];
  const float* pab2  = (const float*)d_in[28];
  const float* caw1  = (const float*)d_in[29];
  const float* cab1  = (const float*)d_in[30];
  const float* caw2  = (const float*)d_in[31];
  const float* cab2  = (const float*)d_in[32];
  const float* aw1   = (const float*)d_in[33];
  const float* ab1   = (const float*)d_in[34];
  const float* aw2   = (const float*)d_in[35];
  const float* ab2   = (const float*)d_in[36];

  float* ws  = (float*)d_ws;
  float* out = (float*)d_out;
  float* st0 = ws;
  float* st1 = ws + 8;
  float* st2 = ws + 16;
  unsigned short* q     = (unsigned short*)(ws + WS_Q);
  unsigned short* k     = (unsigned short*)(ws + WS_K);
  unsigned short* v     = (unsigned short*)(ws + WS_V);
  unsigned short* attpm = (unsigned short*)(ws + WS_ATTPM);
  unsigned short* hid   = (unsigned short*)(ws + WS_Q);
  float* x1  = ws + WS_X1;
  float* x2  = ws + WS_X2;
  float* x3  = ws + WS_X3;
  float* pab = ws + WS_PA;
  float* gpb = ws + WS_GAP;
  float* cab = ws + WS_CA;
  float* bns = ws + WBNS;

  hipMemsetAsync(d_ws, 0, 64*sizeof(float), stream);
  prep_stats_kernel<<<1040, 256, 0, stream>>>(x, st0, qkv1w, qkv2w, proj1w, proj2w,
                                              mw1, mw2, aw1, aw2, paw1,
                                              bng, bnb, bnm, bnv, ws);

  // stage 1: attn k=7 d=1
  gemm_qkv_kernel<<<dim3(256,2), 256, 0, stream>>>(x, st0, lnw, lnb, (unsigned short*)(ws+WQKV1), qkv1b, q, k, v);
  attn_kernel<7,1,13><<<1536, 256, 0, stream>>>(q, k, v, rpb1, attpm);
  gemm_proj_kernel<<<dim3(128,2), 256, 0, stream>>>(attpm, (unsigned short*)(ws+WPROJ1), proj1b,
                                                    x, st0, m1w, m1b, m2w, m2b, x1, st1);

  // stage 2: attn k=5 d=8
  gemm_qkv_kernel<<<dim3(256,2), 256, 0, stream>>>(x1, st1, lnw, lnb, (unsigned short*)(ws+WQKV2), qkv2b, q, k, v);
  attn_kernel<5,8,9><<<1536, 256, 0, stream>>>(q, k, v, rpb2, attpm);
  gemm_proj_kernel<<<dim3(128,2), 256, 0, stream>>>(attpm, (unsigned short*)(ws+WPROJ2), proj2b,
                                                    x1, st1, m1w, m1b, m2w, m2b, x2, st2);

  // stage 3: MLP (sc = x1)
  gemm_mlp1_kernel<<<dim3(256,2), 256, 0, stream>>>(x2, st2, lnw, lnb, (unsigned short*)(ws+WMLP1), mb1, hid);
  gemm_mlp2_kernel<<<dim3(128,2), 256, 0, stream>>>(hid, (unsigned short*)(ws+WMLP2), mb2,
                                                    x1, st2, m1w, m1b, m2w, m2b, x3);

  // stage 4: pa -> gap -> ca -> fused m2a
  pa_kernel<<<256, 256, 0, stream>>>(x3, bns, ws + WPA1T, pab1, paw2, pab2, pab);
  gap_kernel<<<384, 256, 0, stream>>>(x3, bns, pab, gpb);
  ca_kernel<<<4, 128, 0, stream>>>(gpb, caw1, cab1, caw2, cab2, cab);
  gemm_m2a_kernel<<<256, 256, 0, stream>>>(x3, bns, pab, cab, (unsigned short*)(ws+WM2A1), ab1,
                                           (unsigned short*)(ws+WM2A2), ab2, x3, out);
}

// Round 11
// 293.982 us; speedup vs baseline: 10.4771x; 1.0227x over previous
//
#include <hip/hip_runtime.h>
#include <math.h>

#define CC 96
#define NP 4096
#define NHEADS 6
#define NELEMF 393216.0f
#define EPSF 1e-5f

typedef __attribute__((ext_vector_type(8))) short bf16x8;
typedef __attribute__((ext_vector_type(4))) float f32x4;
#define MFMA16(a,b,c) __builtin_amdgcn_mfma_f32_16x16x32_bf16(a,b,c,0,0,0)

// ---- workspace layout (float offsets) ----
#define WQKV1  64
#define WQKV2  (WQKV1+13824)
#define WPROJ1 (WQKV2+13824)
#define WPROJ2 (WPROJ1+4608)
#define WMLP1  (WPROJ2+4608)
#define WMLP2  (WMLP1+18432)
#define WM2A1  (WMLP2+18432)
#define WM2A2  (WM2A1+4608)
#define WPA1T  (WM2A2+4608)
#define WBNS   (WPA1T+1152)
#define WS_Q   870784
#define WS_K   (WS_Q+786432)
#define WS_V   (WS_K+786432)
#define WS_ATTPM (WS_V+786432)
#define WS_X1  (WS_ATTPM+786432)  // x1 bf16 (uses half)
#define WS_X2  (WS_X1+1572864)    // x2 bf16 (uses half)
#define WS_X3  (WS_X2+1572864)    // x3 fp32
#define WS_PA  (WS_X3+1572864)
#define WS_GAP (WS_PA+16384)
#define WS_CA  (WS_GAP+384)

__device__ __forceinline__ float gelu_f(float x){
  return 0.5f * x * (1.0f + erff(x * 0.7071067811865476f));
}
__device__ __forceinline__ float sigmoid_f(float x){
  return 1.0f / (1.0f + __expf(-x));
}
__device__ __forceinline__ unsigned short bfr(float f){
  unsigned int u = __float_as_uint(f);
  u += 0x7fffu + ((u >> 16) & 1u);
  return (unsigned short)(u >> 16);
}
__device__ __forceinline__ float bflo16(unsigned short u){ return __uint_as_float(((unsigned int)u) << 16); }
__device__ __forceinline__ float bflo(unsigned int u){ return __uint_as_float(u << 16); }
__device__ __forceinline__ float bfhi(unsigned int u){ return __uint_as_float(u & 0xffff0000u); }
__device__ __forceinline__ void get_ms(const float* st, int b, float& mean, float& inv, float& stdv){
  float s = st[b], s2 = st[4+b];
  mean = s * (1.0f/NELEMF);
  float var = fmaxf(s2 * (1.0f/NELEMF) - mean*mean, 0.0f);
  stdv = sqrtf(var + EPSF);
  inv = 1.0f / stdv;
}
// residual load/store helpers (fp32 or bf16 stream)
__device__ __forceinline__ float ldf(const float* p, int i){ return p[i]; }
__device__ __forceinline__ float ldf(const unsigned short* p, int i){ return bflo16(p[i]); }
// 4-px vector load for A-tile staging
__device__ __forceinline__ void load4(const float* p, float4& v){ v = *(const float4*)p; }
__device__ __forceinline__ void load4(const unsigned short* p, float4& v){
  ushort4 u = *(const ushort4*)p;
  v.x = bflo16(u.x); v.y = bflo16(u.y); v.z = bflo16(u.z); v.w = bflo16(u.w);
}

// ---- combined: stats(x) for blocks <384, weight prep for blocks >=384 ----
__global__ void prep_stats_kernel(const float* __restrict__ x, float* __restrict__ st,
                             const float* __restrict__ q1, const float* __restrict__ q2,
                             const float* __restrict__ p1, const float* __restrict__ p2,
                             const float* __restrict__ w1, const float* __restrict__ w2,
                             const float* __restrict__ a1, const float* __restrict__ a2,
                             const float* __restrict__ pw1,
                             const float* __restrict__ bg, const float* __restrict__ bb,
                             const float* __restrict__ bm, const float* __restrict__ bv,
                             float* __restrict__ ws){
  if(blockIdx.x < 384){
    int b = blockIdx.x / CC, c = blockIdx.x % CC;
    const float* p = x + (b*CC + c)*NP;
    float s = 0.f, s2 = 0.f;
    for(int i = threadIdx.x; i < NP; i += 256){ float v = p[i]; s += v; s2 = fmaf(v, v, s2); }
    for(int off = 32; off > 0; off >>= 1){ s += __shfl_down(s, off); s2 += __shfl_down(s2, off); }
    __shared__ float ls[8];
    int wid = threadIdx.x >> 6;
    if((threadIdx.x & 63) == 0){ ls[wid] = s; ls[4+wid] = s2; }
    __syncthreads();
    if(threadIdx.x == 0){
      atomicAdd(&st[b],   ls[0]+ls[1]+ls[2]+ls[3]);
      atomicAdd(&st[4+b], ls[4]+ls[5]+ls[6]+ls[7]);
    }
    return;
  }
  int gid = (blockIdx.x - 384)*256 + threadIdx.x;
  if(gid < 27648){ int n = gid/96, c = gid%96; ((unsigned short*)(ws+WQKV1))[gid] = bfr(q1[c*288+n]); }
  else if(gid < 55296){ int g = gid-27648; int n = g/96, c = g%96; ((unsigned short*)(ws+WQKV2))[g] = bfr(q2[c*288+n]); }
  else if(gid < 64512){ int g = gid-55296; int n = g/96, c = g%96; ((unsigned short*)(ws+WPROJ1))[g] = bfr(p1[c*96+n]); }
  else if(gid < 73728){ int g = gid-64512; int n = g/96, c = g%96; ((unsigned short*)(ws+WPROJ2))[g] = bfr(p2[c*96+n]); }
  else if(gid < 110592){ int g = gid-73728; ((unsigned short*)(ws+WMLP1))[g] = bfr(w1[g]); }
  else if(gid < 147456){ int g = gid-110592; ((unsigned short*)(ws+WMLP2))[g] = bfr(w2[g]); }
  else if(gid < 156672){ int g = gid-147456; ((unsigned short*)(ws+WM2A1))[g] = bfr(a1[g]); }
  else if(gid < 165888){ int g = gid-156672; ((unsigned short*)(ws+WM2A2))[g] = bfr(a2[g]); }
  else if(gid < 167040){ int g = gid-165888; int c = g/12, h = g%12; ws[WPA1T + g] = pw1[h*96+c]; }
  else if(gid < 167136){ int c = gid-167040;
    float sc = rsqrtf(bv[c] + EPSF) * bg[c];
    ws[WBNS + c] = sc;
    ws[WBNS + 96 + c] = bb[c] - bm[c]*sc;
  }
}

// ---- fused LN + QKV GEMM: M=64-px block, all 288 N, A read once ----
template<typename AT>
__global__ void __launch_bounds__(256) gemm_qkv_kernel(
    const AT* __restrict__ xin, const float* __restrict__ st,
    const float* __restrict__ lnw, const float* __restrict__ lnb,
    const unsigned short* __restrict__ wT, const float* __restrict__ qb,
    unsigned short* __restrict__ qo, unsigned short* __restrict__ ko, unsigned short* __restrict__ vo){
  __shared__ unsigned short Atl[64*104];
  __shared__ float scl[96], ofs[96];
  int m_base = blockIdx.x*64;
  int b = m_base >> 12, pxl0 = m_base & 4095;
  float mean, inv, stdv; get_ms(st, b, mean, inv, stdv);
  int tid = threadIdx.x;
  if(tid < 96){ float s = inv*lnw[tid]; scl[tid] = s; ofs[tid] = lnb[tid] - mean*s; }
  __syncthreads();
  const AT* src = xin + (size_t)b*CC*NP + pxl0;
  for(int idx = tid; idx < 96*16; idx += 256){
    int c = idx >> 4, p4 = (idx & 15) << 2;
    float4 v; load4(src + (size_t)c*NP + p4, v);
    float s = scl[c], o = ofs[c];
    Atl[(p4+0)*104 + c] = bfr(fmaf(v.x, s, o));
    Atl[(p4+1)*104 + c] = bfr(fmaf(v.y, s, o));
    Atl[(p4+2)*104 + c] = bfr(fmaf(v.z, s, o));
    Atl[(p4+3)*104 + c] = bfr(fmaf(v.w, s, o));
  }
  __syncthreads();
  int w = tid >> 6, lane = tid & 63, ml = lane & 15, q = lane >> 4;
  const unsigned short* arow = Atl + (w*16 + ml)*104;
  bf16x8 av[3];
  #pragma unroll
  for(int ks = 0; ks < 3; ++ks) av[ks] = *(const bf16x8*)(arow + ks*32 + q*8);
  f32x4 z = {0.f,0.f,0.f,0.f};
  #pragma unroll
  for(int g = 0; g < 6; ++g){
    f32x4 acc[3] = {z, z, z};
    #pragma unroll
    for(int ks = 0; ks < 3; ++ks){
      #pragma unroll
      for(int gg = 0; gg < 3; ++gg){
        bf16x8 bv = *(const bf16x8*)(wT + (g*48 + gg*16 + ml)*96 + ks*32 + q*8);
        acc[gg] = MFMA16(av[ks], bv, acc[gg]);
      }
    }
    #pragma unroll
    for(int gg = 0; gg < 3; ++gg){
      int nfb = g*48 + gg*16;
      int t = nfb/96, head = (nfb%96) >> 4;
      float scale = (t == 0) ? 0.25f : 1.0f;
      unsigned short* dst = (t == 0) ? qo : (t == 1) ? ko : vo;
      float bias = qb[nfb + ml];
      #pragma unroll
      for(int r = 0; r < 4; ++r){
        int pxl = pxl0 + w*16 + q*4 + r;
        dst[(((size_t)(b*NHEADS + head))*NP + pxl)*16 + ml] = bfr((acc[gg][r] + bias)*scale);
      }
    }
  }
}

// ---- proj GEMM: attpm @ projT -> c-major bf16 + residual + fused fp32 stats (M=128) ----
template<typename SCT>
__global__ void __launch_bounds__(256) gemm_proj_kernel(
    const unsigned short* __restrict__ attpm, const unsigned short* __restrict__ wT,
    const float* __restrict__ pb, const SCT* __restrict__ scx, const float* __restrict__ st,
    const float* __restrict__ m1w, const float* __restrict__ m1b,
    const float* __restrict__ m2w, const float* __restrict__ m2b,
    unsigned short* __restrict__ dst, float* __restrict__ st_out){
  int w = threadIdx.x >> 6, lane = threadIdx.x & 63;
  int ml = lane & 15, q = lane >> 4;
  int m_base = blockIdx.x*128 + w*32;
  int n0 = blockIdx.y*48;
  f32x4 acc[2][3];
  f32x4 z = {0.f,0.f,0.f,0.f};
  #pragma unroll
  for(int f=0; f<2; ++f) for(int g=0; g<3; ++g) acc[f][g] = z;
  {
    const bf16x8* a0 = (const bf16x8*)(attpm + (size_t)(m_base + ml)*96 + q*8);
    const bf16x8* a1 = (const bf16x8*)(attpm + (size_t)(m_base + 16 + ml)*96 + q*8);
    #pragma unroll
    for(int ks = 0; ks < 3; ++ks){
      bf16x8 av0 = a0[ks*4], av1 = a1[ks*4];
      #pragma unroll
      for(int g = 0; g < 3; ++g){
        bf16x8 bv = *(const bf16x8*)(wT + (n0 + g*16 + ml)*96 + ks*32 + q*8);
        acc[0][g] = MFMA16(av0, bv, acc[0][g]);
        acc[1][g] = MFMA16(av1, bv, acc[1][g]);
      }
    }
  }
  __shared__ float T[48*133];
  #pragma unroll
  for(int f = 0; f < 2; ++f)
    #pragma unroll
    for(int g = 0; g < 3; ++g)
      #pragma unroll
      for(int r = 0; r < 4; ++r)
        T[(g*16 + ml)*133 + w*32 + f*16 + q*4 + r] = acc[f][g][r];
  __syncthreads();
  int b = (blockIdx.x*128) >> 12, pxl0 = (blockIdx.x*128) & 4095;
  float mean, inv, stdv; get_ms(st, b, mean, inv, stdv);
  float s = 0.f, s2 = 0.f;
  for(int idx = threadIdx.x; idx < 48*128; idx += 256){
    int row = idx >> 7, px = idx & 127;
    int n = n0 + row;
    float rsf = fmaf(m1w[n], stdv, m1b[n]);
    float rbf = fmaf(m2w[n], mean, m2b[n]);
    int ad = (b*CC + n)*NP + pxl0 + px;
    float val = ldf(scx, ad) + (T[row*133 + px] + pb[n])*rsf + rbf;
    dst[ad] = bfr(val);
    s += val; s2 = fmaf(val, val, s2);
  }
  for(int off = 32; off > 0; off >>= 1){ s += __shfl_down(s, off); s2 += __shfl_down(s2, off); }
  __shared__ float ls[8];
  int wid = threadIdx.x >> 6;
  if((threadIdx.x & 63) == 0){ ls[wid] = s; ls[4+wid] = s2; }
  __syncthreads();
  if(threadIdx.x == 0){
    atomicAdd(&st_out[b],   ls[0]+ls[1]+ls[2]+ls[3]);
    atomicAdd(&st_out[4+b], ls[4]+ls[5]+ls[6]+ls[7]);
  }
}

// ---- fused LN + mlp1 GEMM: M=64, all 384 N -> relu -> hid bf16 [16384][384] ----
__global__ void __launch_bounds__(256) gemm_mlp1_kernel(
    const unsigned short* __restrict__ xin, const float* __restrict__ st,
    const float* __restrict__ lnw, const float* __restrict__ lnb,
    const unsigned short* __restrict__ wT, const float* __restrict__ b1,
    unsigned short* __restrict__ hid){
  __shared__ unsigned short Atl[64*104];
  __shared__ float scl[96], ofs[96];
  int m_base = blockIdx.x*64;
  int b = m_base >> 12, pxl0 = m_base & 4095;
  float mean, inv, stdv; get_ms(st, b, mean, inv, stdv);
  int tid = threadIdx.x;
  if(tid < 96){ float s = inv*lnw[tid]; scl[tid] = s; ofs[tid] = lnb[tid] - mean*s; }
  __syncthreads();
  const unsigned short* src = xin + (size_t)b*CC*NP + pxl0;
  for(int idx = tid; idx < 96*16; idx += 256){
    int c = idx >> 4, p4 = (idx & 15) << 2;
    float4 v; load4(src + (size_t)c*NP + p4, v);
    float s = scl[c], o = ofs[c];
    Atl[(p4+0)*104 + c] = bfr(fmaf(v.x, s, o));
    Atl[(p4+1)*104 + c] = bfr(fmaf(v.y, s, o));
    Atl[(p4+2)*104 + c] = bfr(fmaf(v.z, s, o));
    Atl[(p4+3)*104 + c] = bfr(fmaf(v.w, s, o));
  }
  __syncthreads();
  int w = tid >> 6, lane = tid & 63, ml = lane & 15, q = lane >> 4;
  const unsigned short* arow = Atl + (w*16 + ml)*104;
  bf16x8 av[3];
  #pragma unroll
  for(int ks = 0; ks < 3; ++ks) av[ks] = *(const bf16x8*)(arow + ks*32 + q*8);
  f32x4 z = {0.f,0.f,0.f,0.f};
  #pragma unroll
  for(int g = 0; g < 8; ++g){
    f32x4 acc[3] = {z, z, z};
    #pragma unroll
    for(int ks = 0; ks < 3; ++ks){
      #pragma unroll
      for(int gg = 0; gg < 3; ++gg){
        bf16x8 bv = *(const bf16x8*)(wT + (g*48 + gg*16 + ml)*96 + ks*32 + q*8);
        acc[gg] = MFMA16(av[ks], bv, acc[gg]);
      }
    }
    #pragma unroll
    for(int gg = 0; gg < 3; ++gg){
      int n = g*48 + gg*16 + ml;
      float bias = b1[n];
      #pragma unroll
      for(int r = 0; r < 4; ++r){
        int m = m_base + w*16 + q*4 + r;
        hid[(size_t)m*384 + n] = bfr(fmaxf(acc[gg][r] + bias, 0.f));
      }
    }
  }
}

// ---- mlp2 GEMM (K=384): hid @ mlp2T -> c-major fp32 + residual(x1 bf16) via st2 ----
__global__ void __launch_bounds__(256) gemm_mlp2_kernel(
    const unsigned short* __restrict__ hid, const unsigned short* __restrict__ wT,
    const float* __restrict__ b2, const unsigned short* __restrict__ scx, const float* __restrict__ st,
    const float* __restrict__ m1w, const float* __restrict__ m1b,
    const float* __restrict__ m2w, const float* __restrict__ m2b,
    float* __restrict__ dst){
  int w = threadIdx.x >> 6, lane = threadIdx.x & 63;
  int ml = lane & 15, q = lane >> 4;
  int m_base = blockIdx.x*128 + w*32;
  int n0 = blockIdx.y*48;
  f32x4 acc[2][3];
  f32x4 z = {0.f,0.f,0.f,0.f};
  #pragma unroll
  for(int f=0; f<2; ++f) for(int g=0; g<3; ++g) acc[f][g] = z;
  {
    const bf16x8* a0 = (const bf16x8*)(hid + (size_t)(m_base + ml)*384 + q*8);
    const bf16x8* a1 = (const bf16x8*)(hid + (size_t)(m_base + 16 + ml)*384 + q*8);
    #pragma unroll
    for(int ks = 0; ks < 12; ++ks){
      bf16x8 av0 = a0[ks*4], av1 = a1[ks*4];
      #pragma unroll
      for(int g = 0; g < 3; ++g){
        bf16x8 bv = *(const bf16x8*)(wT + (n0 + g*16 + ml)*384 + ks*32 + q*8);
        acc[0][g] = MFMA16(av0, bv, acc[0][g]);
        acc[1][g] = MFMA16(av1, bv, acc[1][g]);
      }
    }
  }
  __shared__ float T[48*133];
  #pragma unroll
  for(int f = 0; f < 2; ++f)
    #pragma unroll
    for(int g = 0; g < 3; ++g)
      #pragma unroll
      for(int r = 0; r < 4; ++r)
        T[(g*16 + ml)*133 + w*32 + f*16 + q*4 + r] = acc[f][g][r];
  __syncthreads();
  int b = (blockIdx.x*128) >> 12, pxl0 = (blockIdx.x*128) & 4095;
  float mean, inv, stdv; get_ms(st, b, mean, inv, stdv);
  for(int idx = threadIdx.x; idx < 48*128; idx += 256){
    int row = idx >> 7, px = idx & 127;
    int n = n0 + row;
    float rsf = fmaf(m1w[n], stdv, m1b[n]);
    float rbf = fmaf(m2w[n], mean, m2b[n]);
    int ad = (b*CC + n)*NP + pxl0 + px;
    dst[ad] = ldf(scx, ad) + (T[row*133 + px] + b2[n])*rsf + rbf;
  }
}

// ---- fused m2a: BN*pa*ca load -> GEMM1 -> gelu(LDS) -> GEMM2 -> +x3 -> out (M=64) ----
__global__ void __launch_bounds__(256) gemm_m2a_kernel(
    const float* __restrict__ x3, const float* __restrict__ bns,
    const float* __restrict__ pa, const float* __restrict__ ca,
    const unsigned short* __restrict__ w1T, const float* __restrict__ b1,
    const unsigned short* __restrict__ w2T, const float* __restrict__ b2,
    const float* __restrict__ scx, float* __restrict__ outp){
  __shared__ __align__(16) char smbuf[26624];
  __shared__ float scl[96], ofs[96], pal[64];
  unsigned short* Atl = (unsigned short*)smbuf;
  unsigned short* tl2 = (unsigned short*)(smbuf + 13312);
  float* T = (float*)smbuf;
  int m_base = blockIdx.x*64;
  int b = m_base >> 12, pxl0 = m_base & 4095;
  int tid = threadIdx.x;
  if(tid < 96){ float cv = ca[b*96 + tid]; scl[tid] = bns[tid]*cv; ofs[tid] = bns[96+tid]*cv; }
  if(tid >= 128 && tid < 192) pal[tid-128] = pa[m_base + (tid-128)];
  __syncthreads();
  const float* src = x3 + (size_t)b*CC*NP + pxl0;
  for(int idx = tid; idx < 96*16; idx += 256){
    int c = idx >> 4, p4 = (idx & 15) << 2;
    float4 v = *(const float4*)(src + (size_t)c*NP + p4);
    float s = scl[c], o = ofs[c];
    Atl[(p4+0)*104 + c] = bfr(fmaf(v.x, s, o) * pal[p4+0]);
    Atl[(p4+1)*104 + c] = bfr(fmaf(v.y, s, o) * pal[p4+1]);
    Atl[(p4+2)*104 + c] = bfr(fmaf(v.z, s, o) * pal[p4+2]);
    Atl[(p4+3)*104 + c] = bfr(fmaf(v.w, s, o) * pal[p4+3]);
  }
  __syncthreads();
  int w = tid >> 6, lane = tid & 63, ml = lane & 15, q = lane >> 4;
  f32x4 z = {0.f,0.f,0.f,0.f};
  f32x4 acc1[6];
  #pragma unroll
  for(int g=0; g<6; ++g) acc1[g] = z;
  {
    const unsigned short* arow = Atl + (w*16 + ml)*104;
    #pragma unroll
    for(int ks = 0; ks < 3; ++ks){
      bf16x8 av = *(const bf16x8*)(arow + ks*32 + q*8);
      #pragma unroll
      for(int g = 0; g < 6; ++g){
        bf16x8 bv = *(const bf16x8*)(w1T + (g*16 + ml)*96 + ks*32 + q*8);
        acc1[g] = MFMA16(av, bv, acc1[g]);
      }
    }
  }
  #pragma unroll
  for(int g = 0; g < 6; ++g){
    float bias = b1[g*16 + ml];
    #pragma unroll
    for(int r = 0; r < 4; ++r)
      tl2[(w*16 + q*4 + r)*104 + g*16 + ml] = bfr(gelu_f(acc1[g][r] + bias));
  }
  __syncthreads();
  f32x4 acc2[6];
  #pragma unroll
  for(int g=0; g<6; ++g) acc2[g] = z;
  {
    const unsigned short* arow = tl2 + (w*16 + ml)*104;
    #pragma unroll
    for(int ks = 0; ks < 3; ++ks){
      bf16x8 av = *(const bf16x8*)(arow + ks*32 + q*8);
      #pragma unroll
      for(int g = 0; g < 6; ++g){
        bf16x8 bv = *(const bf16x8*)(w2T + (g*16 + ml)*96 + ks*32 + q*8);
        acc2[g] = MFMA16(av, bv, acc2[g]);
      }
    }
  }
  __syncthreads();
  #pragma unroll
  for(int g = 0; g < 6; ++g)
    #pragma unroll
    for(int r = 0; r < 4; ++r)
      T[(g*16 + ml)*68 + w*16 + q*4 + r] = acc2[g][r];
  __syncthreads();
  for(int idx = tid; idx < 96*64; idx += 256){
    int n = idx >> 6, p = idx & 63;
    int ad = (b*CC + n)*NP + pxl0 + p;
    outp[ad] = scx[ad] + T[n*68 + p] + b2[n];
  }
}

// ---- neighborhood attention: bf16 LDS-staged k/v, output pixel-major bf16 ----
template<int K, int D, int RPB>
__global__ void __launch_bounds__(256) attn_kernel(
    const unsigned short* __restrict__ qb, const unsigned short* __restrict__ kb,
    const unsigned short* __restrict__ vb, const float* __restrict__ rpb,
    unsigned short* __restrict__ outp){
  int bh = blockIdx.x >> 6;
  int x = blockIdx.x & 63;
  int head = bh % NHEADS, b = bh / NHEADS;

  int gx = x % D, px = x / D;
  int Lgx = (64 - gx + D - 1) / D;
  int sx = min(max(px - K/2, 0), Lgx - K);

  __shared__ unsigned int sm[2*K*512];
  unsigned int* kl = sm;
  unsigned int* vl = sm + K*512;
  const unsigned int* kg = (const unsigned int*)(kb + (size_t)bh*NP*16);
  const unsigned int* vg = (const unsigned int*)(vb + (size_t)bh*NP*16);
  int tid = threadIdx.x;
  #pragma unroll
  for(int i = 0; i < K; ++i){
    int hh = gx + D*(sx + i);
    ((uint2*)(kl + i*512))[tid] = ((const uint2*)(kg + hh*512))[tid];
    ((uint2*)(vl + i*512))[tid] = ((const uint2*)(vg + hh*512))[tid];
  }
  __syncthreads();

  int pixoff = tid >> 2, t = tid & 3;
  int y = pixoff;
  int pix = x*64 + y;
  uint2 qd = *(const uint2*)(qb + ((size_t)bh*NP + pix)*16 + 4*t);
  float qx = bflo(qd.x), qy = bfhi(qd.x), qz = bflo(qd.y), qw = bfhi(qd.y);

  int gy = y % D, py = y / D;
  int Lgy = (64 - gy + D - 1) / D;
  int sy = min(max(py - K/2, 0), Lgy - K);

  float sc[K*K];
  #pragma unroll
  for(int i = 0; i < K; ++i){
    #pragma unroll
    for(int j = 0; j < K; ++j){
      int ww = gy + D*(sy + j);
      uint2 kv = *(const uint2*)(kl + i*512 + ww*8 + t*2);
      float s = qx*bflo(kv.x);
      s = fmaf(qy, bfhi(kv.x), s);
      s = fmaf(qz, bflo(kv.y), s);
      s = fmaf(qw, bfhi(kv.y), s);
      sc[i*K + j] = s;
    }
  }
  float mx = -1e30f;
  #pragma unroll
  for(int i = 0; i < K; ++i){
    const float* brow = rpb + (head*RPB + (sx + i - px + (K-1)))*RPB + (sy - py + (K-1));
    #pragma unroll
    for(int j = 0; j < K; ++j){
      float s = sc[i*K + j];
      s += __shfl_xor(s, 1);
      s += __shfl_xor(s, 2);
      s += brow[j];
      sc[i*K + j] = s;
      mx = fmaxf(mx, s);
    }
  }
  float sum = 0.f;
  #pragma unroll
  for(int n = 0; n < K*K; ++n){ float e = __expf(sc[n] - mx); sc[n] = e; sum += e; }
  float rs = 1.0f / sum;
  float4 acc = {0,0,0,0};
  #pragma unroll
  for(int i = 0; i < K; ++i){
    #pragma unroll
    for(int j = 0; j < K; ++j){
      int ww = gy + D*(sy + j);
      float wgt = sc[i*K + j] * rs;
      uint2 vv = *(const uint2*)(vl + i*512 + ww*8 + t*2);
      acc.x = fmaf(wgt, bflo(vv.x), acc.x);
      acc.y = fmaf(wgt, bfhi(vv.x), acc.y);
      acc.z = fmaf(wgt, bflo(vv.y), acc.z);
      acc.w = fmaf(wgt, bfhi(vv.y), acc.w);
    }
  }
  ushort4 o4;
  o4.x = bfr(acc.x); o4.y = bfr(acc.y); o4.z = bfr(acc.z); o4.w = bfr(acc.w);
  *(ushort4*)(outp + ((size_t)(b*NP + pix))*96 + head*16 + 4*t) = o4;
}

// ---- pixel attention: 4 lanes per pixel (lane owns 24 channels), 256 blocks ----
__global__ void __launch_bounds__(256) pa_kernel(
    const float* __restrict__ x3, const float* __restrict__ bns,
    const float* __restrict__ w1t, const float* __restrict__ b1,
    const float* __restrict__ w2, const float* __restrict__ b2,
    float* __restrict__ pa){
  int b = blockIdx.x >> 6;
  int px0 = (blockIdx.x & 63)*64;
  int pxq = threadIdx.x >> 2, t = threadIdx.x & 3;
  int p = px0 + pxq;
  float acc[12];
  #pragma unroll
  for(int h = 0; h < 12; ++h) acc[h] = 0.f;
  #pragma unroll 6
  for(int cc = 0; cc < 24; ++cc){
    int c = t*24 + cc;
    float yv = fmaf(x3[(b*CC + c)*NP + p], bns[c], bns[96 + c]);
    #pragma unroll
    for(int h = 0; h < 12; ++h) acc[h] = fmaf(yv, w1t[c*12 + h], acc[h]);
  }
  #pragma unroll
  for(int h = 0; h < 12; ++h){
    acc[h] += __shfl_xor(acc[h], 1);
    acc[h] += __shfl_xor(acc[h], 2);
  }
  float s = b2[0];
  #pragma unroll
  for(int h = 0; h < 12; ++h) s = fmaf(gelu_f(acc[h] + b1[h]), w2[h], s);
  if(t == 0) pa[b*NP + p] = sigmoid_f(s);
}

// ---- global average pool of pa*BN(x3): one block per (b,c), direct write ----
__global__ void gap_kernel(const float* __restrict__ x3, const float* __restrict__ bns,
                           const float* __restrict__ pa, float* __restrict__ gap){
  int b = blockIdx.x / CC, c = blockIdx.x % CC;
  float scb = bns[c], shb = bns[96 + c];
  float s = 0.f;
  for(int i = threadIdx.x; i < NP; i += 256)
    s = fmaf(fmaf(x3[(b*CC + c)*NP + i], scb, shb), pa[b*NP + i], s);
  for(int off = 32; off > 0; off >>= 1) s += __shfl_down(s, off);
  __shared__ float ls[4];
  if((threadIdx.x & 63) == 0) ls[threadIdx.x >> 6] = s;
  __syncthreads();
  if(threadIdx.x == 0) gap[blockIdx.x] = (ls[0]+ls[1]+ls[2]+ls[3]) * (1.0f/4096.0f);
}

// ---- channel attention ----
__global__ void ca_kernel(const float* __restrict__ gap, const float* __restrict__ w1,
                          const float* __restrict__ b1, const float* __restrict__ w2,
                          const float* __restrict__ b2, float* __restrict__ ca){
  int b = blockIdx.x; int o = threadIdx.x;
  __shared__ float g[96], t[96];
  if(o < 96) g[o] = gap[b*96 + o];
  __syncthreads();
  if(o < 96){
    float a = b1[o];
    for(int c = 0; c < 96; ++c) a = fmaf(g[c], w1[o*96 + c], a);
    t[o] = gelu_f(a);
  }
  __syncthreads();
  if(o < 96){
    float a = b2[o];
    for(int c = 0; c < 96; ++c) a = fmaf(t[c], w2[o*96 + c], a);
    ca[b*96 + o] = sigmoid_f(a);
  }
}

extern "C" void kernel_launch(void* const* d_in, const int* in_sizes, int n_in,
                              void* d_out, int out_size, void* d_ws, size_t ws_size,
                              hipStream_t stream){
  (void)in_sizes; (void)n_in; (void)out_size; (void)ws_size;
  const float* x     = (const float*)d_in[0];
  const float* lnw   = (const float*)d_in[1];
  const float* lnb   = (const float*)d_in[2];
  const float* m1w   = (const float*)d_in[3];
  const float* m1b   = (const float*)d_in[4];
  const float* m2w   = (const float*)d_in[5];
  const float* m2b   = (const float*)d_in[6];
  const float* qkv1w = (const float*)d_in[7];
  const float* qkv1b = (const float*)d_in[8];
  const float* proj1w= (const float*)d_in[9];
  const float* proj1b= (const float*)d_in[10];
  const float* rpb1  = (const float*)d_in[11];
  const float* qkv2w = (const float*)d_in[12];
  const float* qkv2b = (const float*)d_in[13];
  const float* proj2w= (const float*)d_in[14];
  const float* proj2b= (const float*)d_in[15];
  const float* rpb2  = (const float*)d_in[16];
  const float* mw1   = (const float*)d_in[17];
  const float* mb1   = (const float*)d_in[18];
  const float* mw2   = (const float*)d_in[19];
  const float* mb2   = (const float*)d_in[20];
  const float* bng   = (const float*)d_in[21];
  const float* bnb   = (const float*)d_in[22];
  const float* bnm   = (const float*)d_in[23];
  const float* bnv   = (const float*)d_in[24];
  const float* paw1  = (const float*)d_in[25];
  const float* pab1  = (const float*)d_in[26];
  const float* paw2  = (const float*)d_in[27];
  const float* pab2  = (const float*)d_in[28];
  const float* caw1  = (const float*)d_in[29];
  const float* cab1  = (const float*)d_in[30];
  const float* caw2  = (const float*)d_in[31];
  const float* cab2  = (const float*)d_in[32];
  const float* aw1   = (const float*)d_in[33];
  const float* ab1   = (const float*)d_in[34];
  const float* aw2   = (const float*)d_in[35];
  const float* ab2   = (const float*)d_in[36];

  float* ws  = (float*)d_ws;
  float* out = (float*)d_out;
  float* st0 = ws;
  float* st1 = ws + 8;
  float* st2 = ws + 16;
  unsigned short* q     = (unsigned short*)(ws + WS_Q);
  unsigned short* k     = (unsigned short*)(ws + WS_K);
  unsigned short* v     = (unsigned short*)(ws + WS_V);
  unsigned short* attpm = (unsigned short*)(ws + WS_ATTPM);
  unsigned short* hid   = (unsigned short*)(ws + WS_Q);
  unsigned short* x1b   = (unsigned short*)(ws + WS_X1);
  unsigned short* x2b   = (unsigned short*)(ws + WS_X2);
  float* x3  = ws + WS_X3;
  float* pab = ws + WS_PA;
  float* gpb = ws + WS_GAP;
  float* cab = ws + WS_CA;
  float* bns = ws + WBNS;

  hipMemsetAsync(d_ws, 0, 64*sizeof(float), stream);
  prep_stats_kernel<<<1040, 256, 0, stream>>>(x, st0, qkv1w, qkv2w, proj1w, proj2w,
                                              mw1, mw2, aw1, aw2, paw1,
                                              bng, bnb, bnm, bnv, ws);

  // stage 1: attn k=7 d=1
  gemm_qkv_kernel<float><<<256, 256, 0, stream>>>(x, st0, lnw, lnb,
      (unsigned short*)(ws+WQKV1), qkv1b, q, k, v);
  attn_kernel<7,1,13><<<1536, 256, 0, stream>>>(q, k, v, rpb1, attpm);
  gemm_proj_kernel<float><<<dim3(128,2), 256, 0, stream>>>(attpm, (unsigned short*)(ws+WPROJ1),
      proj1b, x, st0, m1w, m1b, m2w, m2b, x1b, st1);

  // stage 2: attn k=5 d=8
  gemm_qkv_kernel<unsigned short><<<256, 256, 0, stream>>>(x1b, st1, lnw, lnb,
      (unsigned short*)(ws+WQKV2), qkv2b, q, k, v);
  attn_kernel<5,8,9><<<1536, 256, 0, stream>>>(q, k, v, rpb2, attpm);
  gemm_proj_kernel<unsigned short><<<dim3(128,2), 256, 0, stream>>>(attpm, (unsigned short*)(ws+WPROJ2),
      proj2b, x1b, st1, m1w, m1b, m2w, m2b, x2b, st2);

  // stage 3: MLP (sc = x1)
  gemm_mlp1_kernel<<<256, 256, 0, stream>>>(x2b, st2, lnw, lnb,
      (unsigned short*)(ws+WMLP1), mb1, hid);
  gemm_mlp2_kernel<<<dim3(128,2), 256, 0, stream>>>(hid, (unsigned short*)(ws+WMLP2), mb2,
      x1b, st2, m1w, m1b, m2w, m2b, x3);

  // stage 4: pa -> gap -> ca -> fused m2a
  pa_kernel<<<256, 256, 0, stream>>>(x3, bns, ws + WPA1T, pab1, paw2, pab2, pab);
  gap_kernel<<<384, 256, 0, stream>>>(x3, bns, pab, gpb);
  ca_kernel<<<4, 128, 0, stream>>>(gpb, caw1, cab1, caw2, cab2, cab);
  gemm_m2a_kernel<<<256, 256, 0, stream>>>(x3, bns, pab, cab, (unsigned short*)(ws+WM2A1), ab1,
                                           (unsigned short*)(ws+WM2A2), ab2, x3, out);
}

// Round 12
// 290.994 us; speedup vs baseline: 10.5847x; 1.0103x over previous
//
#include <hip/hip_runtime.h>
#include <math.h>

#define CC 96
#define NP 4096
#define NHEADS 6
#define NELEMF 393216.0f
#define EPSF 1e-5f

typedef __attribute__((ext_vector_type(8))) short bf16x8;
typedef __attribute__((ext_vector_type(4))) float f32x4;
#define MFMA16(a,b,c) __builtin_amdgcn_mfma_f32_16x16x32_bf16(a,b,c,0,0,0)

// ---- workspace layout (float offsets) ----
#define WQKV1  64
#define WQKV2  (WQKV1+13824)
#define WPROJ1 (WQKV2+13824)
#define WPROJ2 (WPROJ1+4608)
#define WMLP1  (WPROJ2+4608)
#define WMLP2  (WMLP1+18432)
#define WM2A1  (WMLP2+18432)
#define WM2A2  (WM2A1+4608)
#define WPA1T  (WM2A2+4608)
#define WBNS   (WPA1T+1152)
#define WS_Q   870784
#define WS_K   (WS_Q+786432)
#define WS_V   (WS_K+786432)
#define WS_ATTPM (WS_V+786432)
#define WS_X1  (WS_ATTPM+786432)  // x1 bf16
#define WS_X2  (WS_X1+1572864)    // x2 bf16
#define WS_X3  (WS_X2+1572864)    // x3 fp32
#define WS_PA  (WS_X3+1572864)
#define WS_GAP (WS_PA+16384)
#define WS_CA  (WS_GAP+384)

__device__ __forceinline__ float gelu_f(float x){
  return 0.5f * x * (1.0f + erff(x * 0.7071067811865476f));
}
__device__ __forceinline__ float sigmoid_f(float x){
  return 1.0f / (1.0f + __expf(-x));
}
__device__ __forceinline__ unsigned short bfr(float f){
  unsigned int u = __float_as_uint(f);
  u += 0x7fffu + ((u >> 16) & 1u);
  return (unsigned short)(u >> 16);
}
__device__ __forceinline__ float bflo16(unsigned short u){ return __uint_as_float(((unsigned int)u) << 16); }
__device__ __forceinline__ float bflo(unsigned int u){ return __uint_as_float(u << 16); }
__device__ __forceinline__ float bfhi(unsigned int u){ return __uint_as_float(u & 0xffff0000u); }
__device__ __forceinline__ void get_ms(const float* st, int b, float& mean, float& inv, float& stdv){
  float s = st[b], s2 = st[4+b];
  mean = s * (1.0f/NELEMF);
  float var = fmaxf(s2 * (1.0f/NELEMF) - mean*mean, 0.0f);
  stdv = sqrtf(var + EPSF);
  inv = 1.0f / stdv;
}
__device__ __forceinline__ float ldf(const float* p, int i){ return p[i]; }
__device__ __forceinline__ float ldf(const unsigned short* p, int i){ return bflo16(p[i]); }
__device__ __forceinline__ void load4(const float* p, float4& v){ v = *(const float4*)p; }
__device__ __forceinline__ void load4(const unsigned short* p, float4& v){
  ushort4 u = *(const ushort4*)p;
  v.x = bflo16(u.x); v.y = bflo16(u.y); v.z = bflo16(u.z); v.w = bflo16(u.w);
}

// ---- combined: stats(x) for blocks <384, weight prep + gap zero for blocks >=384 ----
__global__ void prep_stats_kernel(const float* __restrict__ x, float* __restrict__ st,
                             const float* __restrict__ q1, const float* __restrict__ q2,
                             const float* __restrict__ p1, const float* __restrict__ p2,
                             const float* __restrict__ w1, const float* __restrict__ w2,
                             const float* __restrict__ a1, const float* __restrict__ a2,
                             const float* __restrict__ pw1,
                             const float* __restrict__ bg, const float* __restrict__ bb,
                             const float* __restrict__ bm, const float* __restrict__ bv,
                             float* __restrict__ ws){
  if(blockIdx.x < 384){
    int b = blockIdx.x / CC, c = blockIdx.x % CC;
    const float* p = x + (b*CC + c)*NP;
    float s = 0.f, s2 = 0.f;
    for(int i = threadIdx.x; i < NP; i += 256){ float v = p[i]; s += v; s2 = fmaf(v, v, s2); }
    for(int off = 32; off > 0; off >>= 1){ s += __shfl_down(s, off); s2 += __shfl_down(s2, off); }
    __shared__ float ls[8];
    int wid = threadIdx.x >> 6;
    if((threadIdx.x & 63) == 0){ ls[wid] = s; ls[4+wid] = s2; }
    __syncthreads();
    if(threadIdx.x == 0){
      atomicAdd(&st[b],   ls[0]+ls[1]+ls[2]+ls[3]);
      atomicAdd(&st[4+b], ls[4]+ls[5]+ls[6]+ls[7]);
    }
    return;
  }
  int gid = (blockIdx.x - 384)*256 + threadIdx.x;
  if(gid < 27648){ int n = gid/96, c = gid%96; ((unsigned short*)(ws+WQKV1))[gid] = bfr(q1[c*288+n]); }
  else if(gid < 55296){ int g = gid-27648; int n = g/96, c = g%96; ((unsigned short*)(ws+WQKV2))[g] = bfr(q2[c*288+n]); }
  else if(gid < 64512){ int g = gid-55296; int n = g/96, c = g%96; ((unsigned short*)(ws+WPROJ1))[g] = bfr(p1[c*96+n]); }
  else if(gid < 73728){ int g = gid-64512; int n = g/96, c = g%96; ((unsigned short*)(ws+WPROJ2))[g] = bfr(p2[c*96+n]); }
  else if(gid < 110592){ int g = gid-73728; ((unsigned short*)(ws+WMLP1))[g] = bfr(w1[g]); }
  else if(gid < 147456){ int g = gid-110592; ((unsigned short*)(ws+WMLP2))[g] = bfr(w2[g]); }
  else if(gid < 156672){ int g = gid-147456; ((unsigned short*)(ws+WM2A1))[g] = bfr(a1[g]); }
  else if(gid < 165888){ int g = gid-156672; ((unsigned short*)(ws+WM2A2))[g] = bfr(a2[g]); }
  else if(gid < 167040){ int g = gid-165888; int c = g/12, h = g%12; ws[WPA1T + g] = pw1[h*96+c]; }
  else if(gid < 167136){ int c = gid-167040;
    float sc = rsqrtf(bv[c] + EPSF) * bg[c];
    ws[WBNS + c] = sc;
    ws[WBNS + 96 + c] = bb[c] - bm[c]*sc;
  }
  else if(gid < 167520){ ws[WS_GAP + (gid-167136)] = 0.f; }
}

// ---- fused LN + QKV GEMM: M=64-px block, all 288 N, A read once ----
template<typename AT>
__global__ void __launch_bounds__(256) gemm_qkv_kernel(
    const AT* __restrict__ xin, const float* __restrict__ st,
    const float* __restrict__ lnw, const float* __restrict__ lnb,
    const unsigned short* __restrict__ wT, const float* __restrict__ qb,
    unsigned short* __restrict__ qo, unsigned short* __restrict__ ko, unsigned short* __restrict__ vo){
  __shared__ unsigned short Atl[64*104];
  __shared__ float scl[96], ofs[96];
  int m_base = blockIdx.x*64;
  int b = m_base >> 12, pxl0 = m_base & 4095;
  float mean, inv, stdv; get_ms(st, b, mean, inv, stdv);
  int tid = threadIdx.x;
  if(tid < 96){ float s = inv*lnw[tid]; scl[tid] = s; ofs[tid] = lnb[tid] - mean*s; }
  __syncthreads();
  const AT* src = xin + (size_t)b*CC*NP + pxl0;
  for(int idx = tid; idx < 96*16; idx += 256){
    int c = idx >> 4, p4 = (idx & 15) << 2;
    float4 v; load4(src + (size_t)c*NP + p4, v);
    float s = scl[c], o = ofs[c];
    Atl[(p4+0)*104 + c] = bfr(fmaf(v.x, s, o));
    Atl[(p4+1)*104 + c] = bfr(fmaf(v.y, s, o));
    Atl[(p4+2)*104 + c] = bfr(fmaf(v.z, s, o));
    Atl[(p4+3)*104 + c] = bfr(fmaf(v.w, s, o));
  }
  __syncthreads();
  int w = tid >> 6, lane = tid & 63, ml = lane & 15, q = lane >> 4;
  const unsigned short* arow = Atl + (w*16 + ml)*104;
  bf16x8 av[3];
  #pragma unroll
  for(int ks = 0; ks < 3; ++ks) av[ks] = *(const bf16x8*)(arow + ks*32 + q*8);
  f32x4 z = {0.f,0.f,0.f,0.f};
  #pragma unroll
  for(int g = 0; g < 6; ++g){
    f32x4 acc[3] = {z, z, z};
    #pragma unroll
    for(int ks = 0; ks < 3; ++ks){
      #pragma unroll
      for(int gg = 0; gg < 3; ++gg){
        bf16x8 bv = *(const bf16x8*)(wT + (g*48 + gg*16 + ml)*96 + ks*32 + q*8);
        acc[gg] = MFMA16(av[ks], bv, acc[gg]);
      }
    }
    #pragma unroll
    for(int gg = 0; gg < 3; ++gg){
      int nfb = g*48 + gg*16;
      int t = nfb/96, head = (nfb%96) >> 4;
      float scale = (t == 0) ? 0.25f : 1.0f;
      unsigned short* dst = (t == 0) ? qo : (t == 1) ? ko : vo;
      float bias = qb[nfb + ml];
      #pragma unroll
      for(int r = 0; r < 4; ++r){
        int pxl = pxl0 + w*16 + q*4 + r;
        dst[(((size_t)(b*NHEADS + head))*NP + pxl)*16 + ml] = bfr((acc[gg][r] + bias)*scale);
      }
    }
  }
}

// ---- proj GEMM: attpm @ projT -> c-major bf16 + residual + fused fp32 stats (M=128) ----
template<typename SCT>
__global__ void __launch_bounds__(256) gemm_proj_kernel(
    const unsigned short* __restrict__ attpm, const unsigned short* __restrict__ wT,
    const float* __restrict__ pb, const SCT* __restrict__ scx, const float* __restrict__ st,
    const float* __restrict__ m1w, const float* __restrict__ m1b,
    const float* __restrict__ m2w, const float* __restrict__ m2b,
    unsigned short* __restrict__ dst, float* __restrict__ st_out){
  int w = threadIdx.x >> 6, lane = threadIdx.x & 63;
  int ml = lane & 15, q = lane >> 4;
  int m_base = blockIdx.x*128 + w*32;
  int n0 = blockIdx.y*48;
  f32x4 acc[2][3];
  f32x4 z = {0.f,0.f,0.f,0.f};
  #pragma unroll
  for(int f=0; f<2; ++f) for(int g=0; g<3; ++g) acc[f][g] = z;
  {
    const bf16x8* a0 = (const bf16x8*)(attpm + (size_t)(m_base + ml)*96 + q*8);
    const bf16x8* a1 = (const bf16x8*)(attpm + (size_t)(m_base + 16 + ml)*96 + q*8);
    #pragma unroll
    for(int ks = 0; ks < 3; ++ks){
      bf16x8 av0 = a0[ks*4], av1 = a1[ks*4];
      #pragma unroll
      for(int g = 0; g < 3; ++g){
        bf16x8 bv = *(const bf16x8*)(wT + (n0 + g*16 + ml)*96 + ks*32 + q*8);
        acc[0][g] = MFMA16(av0, bv, acc[0][g]);
        acc[1][g] = MFMA16(av1, bv, acc[1][g]);
      }
    }
  }
  __shared__ float T[48*133];
  #pragma unroll
  for(int f = 0; f < 2; ++f)
    #pragma unroll
    for(int g = 0; g < 3; ++g)
      #pragma unroll
      for(int r = 0; r < 4; ++r)
        T[(g*16 + ml)*133 + w*32 + f*16 + q*4 + r] = acc[f][g][r];
  __syncthreads();
  int b = (blockIdx.x*128) >> 12, pxl0 = (blockIdx.x*128) & 4095;
  float mean, inv, stdv; get_ms(st, b, mean, inv, stdv);
  float s = 0.f, s2 = 0.f;
  for(int idx = threadIdx.x; idx < 48*128; idx += 256){
    int row = idx >> 7, px = idx & 127;
    int n = n0 + row;
    float rsf = fmaf(m1w[n], stdv, m1b[n]);
    float rbf = fmaf(m2w[n], mean, m2b[n]);
    int ad = (b*CC + n)*NP + pxl0 + px;
    float val = ldf(scx, ad) + (T[row*133 + px] + pb[n])*rsf + rbf;
    dst[ad] = bfr(val);
    s += val; s2 = fmaf(val, val, s2);
  }
  for(int off = 32; off > 0; off >>= 1){ s += __shfl_down(s, off); s2 += __shfl_down(s2, off); }
  __shared__ float ls[8];
  int wid = threadIdx.x >> 6;
  if((threadIdx.x & 63) == 0){ ls[wid] = s; ls[4+wid] = s2; }
  __syncthreads();
  if(threadIdx.x == 0){
    atomicAdd(&st_out[b],   ls[0]+ls[1]+ls[2]+ls[3]);
    atomicAdd(&st_out[4+b], ls[4]+ls[5]+ls[6]+ls[7]);
  }
}

// ---- FUSED MLP: LN(x2) -> GEMM1(N=384,relu, hidden in LDS) -> GEMM2(K=384) -> +x1 -> x3 ----
__global__ void __launch_bounds__(256) gemm_mlp_kernel(
    const unsigned short* __restrict__ xin, const float* __restrict__ st,
    const float* __restrict__ lnw, const float* __restrict__ lnb,
    const unsigned short* __restrict__ w1T, const float* __restrict__ b1,
    const unsigned short* __restrict__ w2T, const float* __restrict__ b2,
    const unsigned short* __restrict__ scx,
    const float* __restrict__ m1w, const float* __restrict__ m1b,
    const float* __restrict__ m2w, const float* __restrict__ m2b,
    float* __restrict__ dst){
  __shared__ __align__(16) char smbuf[63488];     // Atl 13312 | hidL 50176
  __shared__ float scl[96], ofs[96];
  unsigned short* Atl  = (unsigned short*)smbuf;
  unsigned short* hidL = (unsigned short*)(smbuf + 13312);   // [64][392] bf16
  float* T = (float*)(smbuf + 13312);                        // aliases hidL (epilogue)
  int m_base = blockIdx.x*64;
  int b = m_base >> 12, pxl0 = m_base & 4095;
  float mean, inv, stdv; get_ms(st, b, mean, inv, stdv);
  int tid = threadIdx.x;
  if(tid < 96){ float s = inv*lnw[tid]; scl[tid] = s; ofs[tid] = lnb[tid] - mean*s; }
  __syncthreads();
  const unsigned short* src = xin + (size_t)b*CC*NP + pxl0;
  for(int idx = tid; idx < 96*16; idx += 256){
    int c = idx >> 4, p4 = (idx & 15) << 2;
    float4 v; load4(src + (size_t)c*NP + p4, v);
    float s = scl[c], o = ofs[c];
    Atl[(p4+0)*104 + c] = bfr(fmaf(v.x, s, o));
    Atl[(p4+1)*104 + c] = bfr(fmaf(v.y, s, o));
    Atl[(p4+2)*104 + c] = bfr(fmaf(v.z, s, o));
    Atl[(p4+3)*104 + c] = bfr(fmaf(v.w, s, o));
  }
  __syncthreads();
  int w = tid >> 6, lane = tid & 63, ml = lane & 15, q = lane >> 4;
  f32x4 z = {0.f,0.f,0.f,0.f};
  // GEMM1: 64x384, hidden -> LDS (relu)
  {
    const unsigned short* arow = Atl + (w*16 + ml)*104;
    bf16x8 av[3];
    #pragma unroll
    for(int ks = 0; ks < 3; ++ks) av[ks] = *(const bf16x8*)(arow + ks*32 + q*8);
    #pragma unroll
    for(int g = 0; g < 8; ++g){
      f32x4 acc[3] = {z, z, z};
      #pragma unroll
      for(int ks = 0; ks < 3; ++ks){
        #pragma unroll
        for(int gg = 0; gg < 3; ++gg){
          bf16x8 bv = *(const bf16x8*)(w1T + (g*48 + gg*16 + ml)*96 + ks*32 + q*8);
          acc[gg] = MFMA16(av[ks], bv, acc[gg]);
        }
      }
      #pragma unroll
      for(int gg = 0; gg < 3; ++gg){
        int n = g*48 + gg*16 + ml;
        float bias = b1[n];
        #pragma unroll
        for(int r = 0; r < 4; ++r)
          hidL[(w*16 + q*4 + r)*392 + n] = bfr(fmaxf(acc[gg][r] + bias, 0.f));
      }
    }
  }
  __syncthreads();
  // GEMM2: 64x96, K=384 from LDS hidden
  f32x4 acc2[6];
  #pragma unroll
  for(int g=0; g<6; ++g) acc2[g] = z;
  {
    const unsigned short* arow = hidL + (w*16 + ml)*392;
    #pragma unroll
    for(int ks = 0; ks < 12; ++ks){
      bf16x8 av = *(const bf16x8*)(arow + ks*32 + q*8);
      #pragma unroll
      for(int g = 0; g < 6; ++g){
        bf16x8 bv = *(const bf16x8*)(w2T + (g*16 + ml)*384 + ks*32 + q*8);
        acc2[g] = MFMA16(av, bv, acc2[g]);
      }
    }
  }
  __syncthreads();      // hidL reads done; region becomes T
  #pragma unroll
  for(int g = 0; g < 6; ++g)
    #pragma unroll
    for(int r = 0; r < 4; ++r)
      T[(g*16 + ml)*68 + w*16 + q*4 + r] = acc2[g][r];
  __syncthreads();
  for(int idx = tid; idx < 96*64; idx += 256){
    int n = idx >> 6, px = idx & 63;
    float rsf = fmaf(m1w[n], stdv, m1b[n]);
    float rbf = fmaf(m2w[n], mean, m2b[n]);
    int ad = (b*CC + n)*NP + pxl0 + px;
    dst[ad] = ldf(scx, ad) + (T[n*68 + px] + b2[n])*rsf + rbf;
  }
}

// ---- fused m2a: BN*pa*ca load -> GEMM1 -> gelu(LDS) -> GEMM2 -> +x3 -> out (M=64) ----
__global__ void __launch_bounds__(256) gemm_m2a_kernel(
    const float* __restrict__ x3, const float* __restrict__ bns,
    const float* __restrict__ pa, const float* __restrict__ ca,
    const unsigned short* __restrict__ w1T, const float* __restrict__ b1,
    const unsigned short* __restrict__ w2T, const float* __restrict__ b2,
    const float* __restrict__ scx, float* __restrict__ outp){
  __shared__ __align__(16) char smbuf[26624];
  __shared__ float scl[96], ofs[96], pal[64];
  unsigned short* Atl = (unsigned short*)smbuf;
  unsigned short* tl2 = (unsigned short*)(smbuf + 13312);
  float* T = (float*)smbuf;
  int m_base = blockIdx.x*64;
  int b = m_base >> 12, pxl0 = m_base & 4095;
  int tid = threadIdx.x;
  if(tid < 96){ float cv = ca[b*96 + tid]; scl[tid] = bns[tid]*cv; ofs[tid] = bns[96+tid]*cv; }
  if(tid >= 128 && tid < 192) pal[tid-128] = pa[m_base + (tid-128)];
  __syncthreads();
  const float* src = x3 + (size_t)b*CC*NP + pxl0;
  for(int idx = tid; idx < 96*16; idx += 256){
    int c = idx >> 4, p4 = (idx & 15) << 2;
    float4 v = *(const float4*)(src + (size_t)c*NP + p4);
    float s = scl[c], o = ofs[c];
    Atl[(p4+0)*104 + c] = bfr(fmaf(v.x, s, o) * pal[p4+0]);
    Atl[(p4+1)*104 + c] = bfr(fmaf(v.y, s, o) * pal[p4+1]);
    Atl[(p4+2)*104 + c] = bfr(fmaf(v.z, s, o) * pal[p4+2]);
    Atl[(p4+3)*104 + c] = bfr(fmaf(v.w, s, o) * pal[p4+3]);
  }
  __syncthreads();
  int w = tid >> 6, lane = tid & 63, ml = lane & 15, q = lane >> 4;
  f32x4 z = {0.f,0.f,0.f,0.f};
  f32x4 acc1[6];
  #pragma unroll
  for(int g=0; g<6; ++g) acc1[g] = z;
  {
    const unsigned short* arow = Atl + (w*16 + ml)*104;
    #pragma unroll
    for(int ks = 0; ks < 3; ++ks){
      bf16x8 av = *(const bf16x8*)(arow + ks*32 + q*8);
      #pragma unroll
      for(int g = 0; g < 6; ++g){
        bf16x8 bv = *(const bf16x8*)(w1T + (g*16 + ml)*96 + ks*32 + q*8);
        acc1[g] = MFMA16(av, bv, acc1[g]);
      }
    }
  }
  #pragma unroll
  for(int g = 0; g < 6; ++g){
    float bias = b1[g*16 + ml];
    #pragma unroll
    for(int r = 0; r < 4; ++r)
      tl2[(w*16 + q*4 + r)*104 + g*16 + ml] = bfr(gelu_f(acc1[g][r] + bias));
  }
  __syncthreads();
  f32x4 acc2[6];
  #pragma unroll
  for(int g=0; g<6; ++g) acc2[g] = z;
  {
    const unsigned short* arow = tl2 + (w*16 + ml)*104;
    #pragma unroll
    for(int ks = 0; ks < 3; ++ks){
      bf16x8 av = *(const bf16x8*)(arow + ks*32 + q*8);
      #pragma unroll
      for(int g = 0; g < 6; ++g){
        bf16x8 bv = *(const bf16x8*)(w2T + (g*16 + ml)*96 + ks*32 + q*8);
        acc2[g] = MFMA16(av, bv, acc2[g]);
      }
    }
  }
  __syncthreads();
  #pragma unroll
  for(int g = 0; g < 6; ++g)
    #pragma unroll
    for(int r = 0; r < 4; ++r)
      T[(g*16 + ml)*68 + w*16 + q*4 + r] = acc2[g][r];
  __syncthreads();
  for(int idx = tid; idx < 96*64; idx += 256){
    int n = idx >> 6, p = idx & 63;
    int ad = (b*CC + n)*NP + pxl0 + p;
    outp[ad] = scx[ad] + T[n*68 + p] + b2[n];
  }
}

// ---- neighborhood attention: bf16 LDS-staged k/v, output pixel-major bf16 ----
template<int K, int D, int RPB>
__global__ void __launch_bounds__(256) attn_kernel(
    const unsigned short* __restrict__ qb, const unsigned short* __restrict__ kb,
    const unsigned short* __restrict__ vb, const float* __restrict__ rpb,
    unsigned short* __restrict__ outp){
  int bh = blockIdx.x >> 6;
  int x = blockIdx.x & 63;
  int head = bh % NHEADS, b = bh / NHEADS;

  int gx = x % D, px = x / D;
  int Lgx = (64 - gx + D - 1) / D;
  int sx = min(max(px - K/2, 0), Lgx - K);

  __shared__ unsigned int sm[2*K*512];
  unsigned int* kl = sm;
  unsigned int* vl = sm + K*512;
  const unsigned int* kg = (const unsigned int*)(kb + (size_t)bh*NP*16);
  const unsigned int* vg = (const unsigned int*)(vb + (size_t)bh*NP*16);
  int tid = threadIdx.x;
  #pragma unroll
  for(int i = 0; i < K; ++i){
    int hh = gx + D*(sx + i);
    ((uint2*)(kl + i*512))[tid] = ((const uint2*)(kg + hh*512))[tid];
    ((uint2*)(vl + i*512))[tid] = ((const uint2*)(vg + hh*512))[tid];
  }
  __syncthreads();

  int pixoff = tid >> 2, t = tid & 3;
  int y = pixoff;
  int pix = x*64 + y;
  uint2 qd = *(const uint2*)(qb + ((size_t)bh*NP + pix)*16 + 4*t);
  float qx = bflo(qd.x), qy = bfhi(qd.x), qz = bflo(qd.y), qw = bfhi(qd.y);

  int gy = y % D, py = y / D;
  int Lgy = (64 - gy + D - 1) / D;
  int sy = min(max(py - K/2, 0), Lgy - K);

  float sc[K*K];
  #pragma unroll
  for(int i = 0; i < K; ++i){
    #pragma unroll
    for(int j = 0; j < K; ++j){
      int ww = gy + D*(sy + j);
      uint2 kv = *(const uint2*)(kl + i*512 + ww*8 + t*2);
      float s = qx*bflo(kv.x);
      s = fmaf(qy, bfhi(kv.x), s);
      s = fmaf(qz, bflo(kv.y), s);
      s = fmaf(qw, bfhi(kv.y), s);
      sc[i*K + j] = s;
    }
  }
  float mx = -1e30f;
  #pragma unroll
  for(int i = 0; i < K; ++i){
    const float* brow = rpb + (head*RPB + (sx + i - px + (K-1)))*RPB + (sy - py + (K-1));
    #pragma unroll
    for(int j = 0; j < K; ++j){
      float s = sc[i*K + j];
      s += __shfl_xor(s, 1);
      s += __shfl_xor(s, 2);
      s += brow[j];
      sc[i*K + j] = s;
      mx = fmaxf(mx, s);
    }
  }
  float sum = 0.f;
  #pragma unroll
  for(int n = 0; n < K*K; ++n){ float e = __expf(sc[n] - mx); sc[n] = e; sum += e; }
  float rs = 1.0f / sum;
  float4 acc = {0,0,0,0};
  #pragma unroll
  for(int i = 0; i < K; ++i){
    #pragma unroll
    for(int j = 0; j < K; ++j){
      int ww = gy + D*(sy + j);
      float wgt = sc[i*K + j] * rs;
      uint2 vv = *(const uint2*)(vl + i*512 + ww*8 + t*2);
      acc.x = fmaf(wgt, bflo(vv.x), acc.x);
      acc.y = fmaf(wgt, bfhi(vv.x), acc.y);
      acc.z = fmaf(wgt, bflo(vv.y), acc.z);
      acc.w = fmaf(wgt, bfhi(vv.y), acc.w);
    }
  }
  ushort4 o4;
  o4.x = bfr(acc.x); o4.y = bfr(acc.y); o4.z = bfr(acc.z); o4.w = bfr(acc.w);
  *(ushort4*)(outp + ((size_t)(b*NP + pix))*96 + head*16 + 4*t) = o4;
}

// ---- fused pixel attention + gap partials: 256 blocks, 4 lanes/pixel ----
__global__ void __launch_bounds__(256) pa_gap_kernel(
    const float* __restrict__ x3, const float* __restrict__ bns,
    const float* __restrict__ w1t, const float* __restrict__ b1,
    const float* __restrict__ w2, const float* __restrict__ b2,
    float* __restrict__ pa, float* __restrict__ gap){
  int b = blockIdx.x >> 6;
  int px0 = (blockIdx.x & 63)*64;
  int pxq = threadIdx.x >> 2, t = threadIdx.x & 3;
  int p = px0 + pxq;
  float yvv[24];
  float acc[12];
  #pragma unroll
  for(int h = 0; h < 12; ++h) acc[h] = 0.f;
  #pragma unroll 6
  for(int cc = 0; cc < 24; ++cc){
    int c = t*24 + cc;
    float yv = fmaf(x3[(b*CC + c)*NP + p], bns[c], bns[96 + c]);
    yvv[cc] = yv;
    #pragma unroll
    for(int h = 0; h < 12; ++h) acc[h] = fmaf(yv, w1t[c*12 + h], acc[h]);
  }
  #pragma unroll
  for(int h = 0; h < 12; ++h){
    acc[h] += __shfl_xor(acc[h], 1);
    acc[h] += __shfl_xor(acc[h], 2);
  }
  float s = b2[0];
  #pragma unroll
  for(int h = 0; h < 12; ++h) s = fmaf(gelu_f(acc[h] + b1[h]), w2[h], s);
  float pav = sigmoid_f(s);
  if(t == 0) pa[b*NP + p] = pav;
  // gap partials: sum over the wave's 16 pixels per channel
  __shared__ float gpart[4*96];
  int w = threadIdx.x >> 6, lane = threadIdx.x & 63;
  #pragma unroll 6
  for(int cc = 0; cc < 24; ++cc){
    float g = yvv[cc] * pav;
    g += __shfl_xor(g, 4);  g += __shfl_xor(g, 8);
    g += __shfl_xor(g, 16); g += __shfl_xor(g, 32);
    if(lane < 4 && lane == t) gpart[w*96 + t*24 + cc] = g;
  }
  __syncthreads();
  if(threadIdx.x < 96){
    int c = threadIdx.x;
    float v = (gpart[c] + gpart[96+c] + gpart[192+c] + gpart[288+c]) * (1.0f/4096.0f);
    atomicAdd(&gap[b*96 + c], v);
  }
}

// ---- channel attention ----
__global__ void ca_kernel(const float* __restrict__ gap, const float* __restrict__ w1,
                          const float* __restrict__ b1, const float* __restrict__ w2,
                          const float* __restrict__ b2, float* __restrict__ ca){
  int b = blockIdx.x; int o = threadIdx.x;
  __shared__ float g[96], t[96];
  if(o < 96) g[o] = gap[b*96 + o];
  __syncthreads();
  if(o < 96){
    float a = b1[o];
    for(int c = 0; c < 96; ++c) a = fmaf(g[c], w1[o*96 + c], a);
    t[o] = gelu_f(a);
  }
  __syncthreads();
  if(o < 96){
    float a = b2[o];
    for(int c = 0; c < 96; ++c) a = fmaf(t[c], w2[o*96 + c], a);
    ca[b*96 + o] = sigmoid_f(a);
  }
}

extern "C" void kernel_launch(void* const* d_in, const int* in_sizes, int n_in,
                              void* d_out, int out_size, void* d_ws, size_t ws_size,
                              hipStream_t stream){
  (void)in_sizes; (void)n_in; (void)out_size; (void)ws_size;
  const float* x     = (const float*)d_in[0];
  const float* lnw   = (const float*)d_in[1];
  const float* lnb   = (const float*)d_in[2];
  const float* m1w   = (const float*)d_in[3];
  const float* m1b   = (const float*)d_in[4];
  const float* m2w   = (const float*)d_in[5];
  const float* m2b   = (const float*)d_in[6];
  const float* qkv1w = (const float*)d_in[7];
  const float* qkv1b = (const float*)d_in[8];
  const float* proj1w= (const float*)d_in[9];
  const float* proj1b= (const float*)d_in[10];
  const float* rpb1  = (const float*)d_in[11];
  const float* qkv2w = (const float*)d_in[12];
  const float* qkv2b = (const float*)d_in[13];
  const float* proj2w= (const float*)d_in[14];
  const float* proj2b= (const float*)d_in[15];
  const float* rpb2  = (const float*)d_in[16];
  const float* mw1   = (const float*)d_in[17];
  const float* mb1   = (const float*)d_in[18];
  const float* mw2   = (const float*)d_in[19];
  const float* mb2   = (const float*)d_in[20];
  const float* bng   = (const float*)d_in[21];
  const float* bnb   = (const float*)d_in[22];
  const float* bnm   = (const float*)d_in[23];
  const float* bnv   = (const float*)d_in[24];
  const float* paw1  = (const float*)d_in[25];
  const float* pab1  = (const float*)d_in[26];
  const float* paw2  = (const float*)d_in[27];
  const float* pab2  = (const float*)d_in[28];
  const float* caw1  = (const float*)d_in[29];
  const float* cab1  = (const float*)d_in[30];
  const float* caw2  = (const float*)d_in[31];
  const float* cab2  = (const float*)d_in[32];
  const float* aw1   = (const float*)d_in[33];
  const float* ab1   = (const float*)d_in[34];
  const float* aw2   = (const float*)d_in[35];
  const float* ab2   = (const float*)d_in[36];

  float* ws  = (float*)d_ws;
  float* out = (float*)d_out;
  float* st0 = ws;
  float* st1 = ws + 8;
  float* st2 = ws + 16;
  unsigned short* q     = (unsigned short*)(ws + WS_Q);
  unsigned short* k     = (unsigned short*)(ws + WS_K);
  unsigned short* v     = (unsigned short*)(ws + WS_V);
  unsigned short* attpm = (unsigned short*)(ws + WS_ATTPM);
  unsigned short* x1b   = (unsigned short*)(ws + WS_X1);
  unsigned short* x2b   = (unsigned short*)(ws + WS_X2);
  float* x3  = ws + WS_X3;
  float* pab = ws + WS_PA;
  float* gpb = ws + WS_GAP;
  float* cab = ws + WS_CA;
  float* bns = ws + WBNS;

  hipMemsetAsync(d_ws, 0, 64*sizeof(float), stream);
  prep_stats_kernel<<<1040, 256, 0, stream>>>(x, st0, qkv1w, qkv2w, proj1w, proj2w,
                                              mw1, mw2, aw1, aw2, paw1,
                                              bng, bnb, bnm, bnv, ws);

  // stage 1: attn k=7 d=1
  gemm_qkv_kernel<float><<<256, 256, 0, stream>>>(x, st0, lnw, lnb,
      (unsigned short*)(ws+WQKV1), qkv1b, q, k, v);
  attn_kernel<7,1,13><<<1536, 256, 0, stream>>>(q, k, v, rpb1, attpm);
  gemm_proj_kernel<float><<<dim3(128,2), 256, 0, stream>>>(attpm, (unsigned short*)(ws+WPROJ1),
      proj1b, x, st0, m1w, m1b, m2w, m2b, x1b, st1);

  // stage 2: attn k=5 d=8
  gemm_qkv_kernel<unsigned short><<<256, 256, 0, stream>>>(x1b, st1, lnw, lnb,
      (unsigned short*)(ws+WQKV2), qkv2b, q, k, v);
  attn_kernel<5,8,9><<<1536, 256, 0, stream>>>(q, k, v, rpb2, attpm);
  gemm_proj_kernel<unsigned short><<<dim3(128,2), 256, 0, stream>>>(attpm, (unsigned short*)(ws+WPROJ2),
      proj2b, x1b, st1, m1w, m1b, m2w, m2b, x2b, st2);

  // stage 3: fused MLP (sc = x1)
  gemm_mlp_kernel<<<256, 256, 0, stream>>>(x2b, st2, lnw, lnb,
      (unsigned short*)(ws+WMLP1), mb1, (unsigned short*)(ws+WMLP2), mb2,
      x1b, m1w, m1b, m2w, m2b, x3);

  // stage 4: pa(+gap) -> ca -> fused m2a
  pa_gap_kernel<<<256, 256, 0, stream>>>(x3, bns, ws + WPA1T, pab1, paw2, pab2, pab, gpb);
  ca_kernel<<<4, 128, 0, stream>>>(gpb, caw1, cab1, caw2, cab2, cab);
  gemm_m2a_kernel<<<256, 256, 0, stream>>>(x3, bns, pab, cab, (unsigned short*)(ws+WM2A1), ab1,
                                           (unsigned short*)(ws+WM2A2), ab2, x3, out);
}

// Round 13
// 289.658 us; speedup vs baseline: 10.6335x; 1.0046x over previous
//
#include <hip/hip_runtime.h>
#include <math.h>

#define CC 96
#define NP 4096
#define NHEADS 6
#define NELEMF 393216.0f
#define EPSF 1e-5f

typedef __attribute__((ext_vector_type(8))) short bf16x8;
typedef __attribute__((ext_vector_type(4))) float f32x4;
#define MFMA16(a,b,c) __builtin_amdgcn_mfma_f32_16x16x32_bf16(a,b,c,0,0,0)

// ---- workspace layout (float offsets) ----
#define WQKV1  64
#define WQKV2  (WQKV1+13824)
#define WPROJ1 (WQKV2+13824)
#define WPROJ2 (WPROJ1+4608)
#define WMLP1  (WPROJ2+4608)
#define WMLP2  (WMLP1+18432)
#define WM2A1  (WMLP2+18432)
#define WM2A2  (WM2A1+4608)
#define WPA1T  (WM2A2+4608)
#define WBNS   (WPA1T+1152)
#define WCA1T  (WBNS+192)          // caw1^T fp32 96x96
#define WCA2T  (WCA1T+9216)        // caw2^T fp32 96x96
#define WS_Q   870784
#define WS_K   (WS_Q+786432)
#define WS_V   (WS_K+786432)
#define WS_ATTPM (WS_V+786432)
#define WS_X1  (WS_ATTPM+786432)  // x1 bf16
#define WS_X2  (WS_X1+1572864)    // x2 bf16
#define WS_X3  (WS_X2+1572864)    // x3 fp32
#define WS_PA  (WS_X3+1572864)
#define WS_GAP (WS_PA+16384)

__device__ __forceinline__ float gelu_f(float x){
  return 0.5f * x * (1.0f + erff(x * 0.7071067811865476f));
}
__device__ __forceinline__ float sigmoid_f(float x){
  return 1.0f / (1.0f + __expf(-x));
}
__device__ __forceinline__ unsigned short bfr(float f){
  unsigned int u = __float_as_uint(f);
  u += 0x7fffu + ((u >> 16) & 1u);
  return (unsigned short)(u >> 16);
}
__device__ __forceinline__ float bflo16(unsigned short u){ return __uint_as_float(((unsigned int)u) << 16); }
__device__ __forceinline__ float bflo(unsigned int u){ return __uint_as_float(u << 16); }
__device__ __forceinline__ float bfhi(unsigned int u){ return __uint_as_float(u & 0xffff0000u); }
__device__ __forceinline__ void get_ms(const float* st, int b, float& mean, float& inv, float& stdv){
  float s = st[b], s2 = st[4+b];
  mean = s * (1.0f/NELEMF);
  float var = fmaxf(s2 * (1.0f/NELEMF) - mean*mean, 0.0f);
  stdv = sqrtf(var + EPSF);
  inv = 1.0f / stdv;
}
__device__ __forceinline__ float ldf(const float* p, int i){ return p[i]; }
__device__ __forceinline__ float ldf(const unsigned short* p, int i){ return bflo16(p[i]); }
__device__ __forceinline__ void load4(const float* p, float4& v){ v = *(const float4*)p; }
__device__ __forceinline__ void load4(const unsigned short* p, float4& v){
  ushort4 u = *(const ushort4*)p;
  v.x = bflo16(u.x); v.y = bflo16(u.y); v.z = bflo16(u.z); v.w = bflo16(u.w);
}

// ---- combined: stats(x) for blocks <384, weight prep + gap zero for blocks >=384 ----
__global__ void prep_stats_kernel(const float* __restrict__ x, float* __restrict__ st,
                             const float* __restrict__ q1, const float* __restrict__ q2,
                             const float* __restrict__ p1, const float* __restrict__ p2,
                             const float* __restrict__ w1, const float* __restrict__ w2,
                             const float* __restrict__ a1, const float* __restrict__ a2,
                             const float* __restrict__ pw1,
                             const float* __restrict__ bg, const float* __restrict__ bb,
                             const float* __restrict__ bm, const float* __restrict__ bv,
                             const float* __restrict__ cw1, const float* __restrict__ cw2,
                             float* __restrict__ ws){
  if(blockIdx.x < 384){
    int b = blockIdx.x / CC, c = blockIdx.x % CC;
    const float* p = x + (b*CC + c)*NP;
    float s = 0.f, s2 = 0.f;
    for(int i = threadIdx.x; i < NP; i += 256){ float v = p[i]; s += v; s2 = fmaf(v, v, s2); }
    for(int off = 32; off > 0; off >>= 1){ s += __shfl_down(s, off); s2 += __shfl_down(s2, off); }
    __shared__ float ls[8];
    int wid = threadIdx.x >> 6;
    if((threadIdx.x & 63) == 0){ ls[wid] = s; ls[4+wid] = s2; }
    __syncthreads();
    if(threadIdx.x == 0){
      atomicAdd(&st[b],   ls[0]+ls[1]+ls[2]+ls[3]);
      atomicAdd(&st[4+b], ls[4]+ls[5]+ls[6]+ls[7]);
    }
    return;
  }
  int gid = (blockIdx.x - 384)*256 + threadIdx.x;
  if(gid < 27648){ int n = gid/96, c = gid%96; ((unsigned short*)(ws+WQKV1))[gid] = bfr(q1[c*288+n]); }
  else if(gid < 55296){ int g = gid-27648; int n = g/96, c = g%96; ((unsigned short*)(ws+WQKV2))[g] = bfr(q2[c*288+n]); }
  else if(gid < 64512){ int g = gid-55296; int n = g/96, c = g%96; ((unsigned short*)(ws+WPROJ1))[g] = bfr(p1[c*96+n]); }
  else if(gid < 73728){ int g = gid-64512; int n = g/96, c = g%96; ((unsigned short*)(ws+WPROJ2))[g] = bfr(p2[c*96+n]); }
  else if(gid < 110592){ int g = gid-73728; ((unsigned short*)(ws+WMLP1))[g] = bfr(w1[g]); }
  else if(gid < 147456){ int g = gid-110592; ((unsigned short*)(ws+WMLP2))[g] = bfr(w2[g]); }
  else if(gid < 156672){ int g = gid-147456; ((unsigned short*)(ws+WM2A1))[g] = bfr(a1[g]); }
  else if(gid < 165888){ int g = gid-156672; ((unsigned short*)(ws+WM2A2))[g] = bfr(a2[g]); }
  else if(gid < 167040){ int g = gid-165888; int c = g/12, h = g%12; ws[WPA1T + g] = pw1[h*96+c]; }
  else if(gid < 167136){ int c = gid-167040;
    float sc = rsqrtf(bv[c] + EPSF) * bg[c];
    ws[WBNS + c] = sc;
    ws[WBNS + 96 + c] = bb[c] - bm[c]*sc;
  }
  else if(gid < 167520){ ws[WS_GAP + (gid-167136)] = 0.f; }
  else if(gid < 176736){ int g = gid-167520; int o = g/96, c = g%96; ws[WCA1T + c*96 + o] = cw1[g]; }
  else if(gid < 185952){ int g = gid-176736; int o = g/96, c = g%96; ws[WCA2T + c*96 + o] = cw2[g]; }
}

// ---- fused LN + QKV GEMM: M=64-px block, all 288 N, A read once ----
template<typename AT>
__global__ void __launch_bounds__(256) gemm_qkv_kernel(
    const AT* __restrict__ xin, const float* __restrict__ st,
    const float* __restrict__ lnw, const float* __restrict__ lnb,
    const unsigned short* __restrict__ wT, const float* __restrict__ qb,
    unsigned short* __restrict__ qo, unsigned short* __restrict__ ko, unsigned short* __restrict__ vo){
  __shared__ unsigned short Atl[64*104];
  __shared__ float scl[96], ofs[96];
  int m_base = blockIdx.x*64;
  int b = m_base >> 12, pxl0 = m_base & 4095;
  float mean, inv, stdv; get_ms(st, b, mean, inv, stdv);
  int tid = threadIdx.x;
  if(tid < 96){ float s = inv*lnw[tid]; scl[tid] = s; ofs[tid] = lnb[tid] - mean*s; }
  __syncthreads();
  const AT* src = xin + (size_t)b*CC*NP + pxl0;
  for(int idx = tid; idx < 96*16; idx += 256){
    int c = idx >> 4, p4 = (idx & 15) << 2;
    float4 v; load4(src + (size_t)c*NP + p4, v);
    float s = scl[c], o = ofs[c];
    Atl[(p4+0)*104 + c] = bfr(fmaf(v.x, s, o));
    Atl[(p4+1)*104 + c] = bfr(fmaf(v.y, s, o));
    Atl[(p4+2)*104 + c] = bfr(fmaf(v.z, s, o));
    Atl[(p4+3)*104 + c] = bfr(fmaf(v.w, s, o));
  }
  __syncthreads();
  int w = tid >> 6, lane = tid & 63, ml = lane & 15, q = lane >> 4;
  const unsigned short* arow = Atl + (w*16 + ml)*104;
  bf16x8 av[3];
  #pragma unroll
  for(int ks = 0; ks < 3; ++ks) av[ks] = *(const bf16x8*)(arow + ks*32 + q*8);
  f32x4 z = {0.f,0.f,0.f,0.f};
  #pragma unroll
  for(int g = 0; g < 6; ++g){
    f32x4 acc[3] = {z, z, z};
    #pragma unroll
    for(int ks = 0; ks < 3; ++ks){
      #pragma unroll
      for(int gg = 0; gg < 3; ++gg){
        bf16x8 bv = *(const bf16x8*)(wT + (g*48 + gg*16 + ml)*96 + ks*32 + q*8);
        acc[gg] = MFMA16(av[ks], bv, acc[gg]);
      }
    }
    #pragma unroll
    for(int gg = 0; gg < 3; ++gg){
      int nfb = g*48 + gg*16;
      int t = nfb/96, head = (nfb%96) >> 4;
      float scale = (t == 0) ? 0.25f : 1.0f;
      unsigned short* dst = (t == 0) ? qo : (t == 1) ? ko : vo;
      float bias = qb[nfb + ml];
      #pragma unroll
      for(int r = 0; r < 4; ++r){
        int pxl = pxl0 + w*16 + q*4 + r;
        dst[(((size_t)(b*NHEADS + head))*NP + pxl)*16 + ml] = bfr((acc[gg][r] + bias)*scale);
      }
    }
  }
}

// ---- proj GEMM: attpm @ projT -> c-major bf16 + residual + fused fp32 stats (M=128) ----
template<typename SCT>
__global__ void __launch_bounds__(256) gemm_proj_kernel(
    const unsigned short* __restrict__ attpm, const unsigned short* __restrict__ wT,
    const float* __restrict__ pb, const SCT* __restrict__ scx, const float* __restrict__ st,
    const float* __restrict__ m1w, const float* __restrict__ m1b,
    const float* __restrict__ m2w, const float* __restrict__ m2b,
    unsigned short* __restrict__ dst, float* __restrict__ st_out){
  int w = threadIdx.x >> 6, lane = threadIdx.x & 63;
  int ml = lane & 15, q = lane >> 4;
  int m_base = blockIdx.x*128 + w*32;
  int n0 = blockIdx.y*48;
  f32x4 acc[2][3];
  f32x4 z = {0.f,0.f,0.f,0.f};
  #pragma unroll
  for(int f=0; f<2; ++f) for(int g=0; g<3; ++g) acc[f][g] = z;
  {
    const bf16x8* a0 = (const bf16x8*)(attpm + (size_t)(m_base + ml)*96 + q*8);
    const bf16x8* a1 = (const bf16x8*)(attpm + (size_t)(m_base + 16 + ml)*96 + q*8);
    #pragma unroll
    for(int ks = 0; ks < 3; ++ks){
      bf16x8 av0 = a0[ks*4], av1 = a1[ks*4];
      #pragma unroll
      for(int g = 0; g < 3; ++g){
        bf16x8 bv = *(const bf16x8*)(wT + (n0 + g*16 + ml)*96 + ks*32 + q*8);
        acc[0][g] = MFMA16(av0, bv, acc[0][g]);
        acc[1][g] = MFMA16(av1, bv, acc[1][g]);
      }
    }
  }
  __shared__ float T[48*133];
  #pragma unroll
  for(int f = 0; f < 2; ++f)
    #pragma unroll
    for(int g = 0; g < 3; ++g)
      #pragma unroll
      for(int r = 0; r < 4; ++r)
        T[(g*16 + ml)*133 + w*32 + f*16 + q*4 + r] = acc[f][g][r];
  __syncthreads();
  int b = (blockIdx.x*128) >> 12, pxl0 = (blockIdx.x*128) & 4095;
  float mean, inv, stdv; get_ms(st, b, mean, inv, stdv);
  float s = 0.f, s2 = 0.f;
  for(int idx = threadIdx.x; idx < 48*128; idx += 256){
    int row = idx >> 7, px = idx & 127;
    int n = n0 + row;
    float rsf = fmaf(m1w[n], stdv, m1b[n]);
    float rbf = fmaf(m2w[n], mean, m2b[n]);
    int ad = (b*CC + n)*NP + pxl0 + px;
    float val = ldf(scx, ad) + (T[row*133 + px] + pb[n])*rsf + rbf;
    dst[ad] = bfr(val);
    s += val; s2 = fmaf(val, val, s2);
  }
  for(int off = 32; off > 0; off >>= 1){ s += __shfl_down(s, off); s2 += __shfl_down(s2, off); }
  __shared__ float ls[8];
  int wid = threadIdx.x >> 6;
  if((threadIdx.x & 63) == 0){ ls[wid] = s; ls[4+wid] = s2; }
  __syncthreads();
  if(threadIdx.x == 0){
    atomicAdd(&st_out[b],   ls[0]+ls[1]+ls[2]+ls[3]);
    atomicAdd(&st_out[4+b], ls[4]+ls[5]+ls[6]+ls[7]);
  }
}

// ---- FUSED MLP: LN(x2) -> GEMM1(N=384,relu, hidden in LDS) -> GEMM2(K=384) -> +x1 -> x3 ----
__global__ void __launch_bounds__(256) gemm_mlp_kernel(
    const unsigned short* __restrict__ xin, const float* __restrict__ st,
    const float* __restrict__ lnw, const float* __restrict__ lnb,
    const unsigned short* __restrict__ w1T, const float* __restrict__ b1,
    const unsigned short* __restrict__ w2T, const float* __restrict__ b2,
    const unsigned short* __restrict__ scx,
    const float* __restrict__ m1w, const float* __restrict__ m1b,
    const float* __restrict__ m2w, const float* __restrict__ m2b,
    float* __restrict__ dst){
  __shared__ __align__(16) char smbuf[63488];     // Atl 13312 | hidL 50176
  __shared__ float scl[96], ofs[96];
  unsigned short* Atl  = (unsigned short*)smbuf;
  unsigned short* hidL = (unsigned short*)(smbuf + 13312);   // [64][392] bf16
  float* T = (float*)(smbuf + 13312);                        // aliases hidL (epilogue)
  int m_base = blockIdx.x*64;
  int b = m_base >> 12, pxl0 = m_base & 4095;
  float mean, inv, stdv; get_ms(st, b, mean, inv, stdv);
  int tid = threadIdx.x;
  if(tid < 96){ float s = inv*lnw[tid]; scl[tid] = s; ofs[tid] = lnb[tid] - mean*s; }
  __syncthreads();
  const unsigned short* src = xin + (size_t)b*CC*NP + pxl0;
  for(int idx = tid; idx < 96*16; idx += 256){
    int c = idx >> 4, p4 = (idx & 15) << 2;
    float4 v; load4(src + (size_t)c*NP + p4, v);
    float s = scl[c], o = ofs[c];
    Atl[(p4+0)*104 + c] = bfr(fmaf(v.x, s, o));
    Atl[(p4+1)*104 + c] = bfr(fmaf(v.y, s, o));
    Atl[(p4+2)*104 + c] = bfr(fmaf(v.z, s, o));
    Atl[(p4+3)*104 + c] = bfr(fmaf(v.w, s, o));
  }
  __syncthreads();
  int w = tid >> 6, lane = tid & 63, ml = lane & 15, q = lane >> 4;
  f32x4 z = {0.f,0.f,0.f,0.f};
  // GEMM1: 64x384, hidden -> LDS (relu)
  {
    const unsigned short* arow = Atl + (w*16 + ml)*104;
    bf16x8 av[3];
    #pragma unroll
    for(int ks = 0; ks < 3; ++ks) av[ks] = *(const bf16x8*)(arow + ks*32 + q*8);
    #pragma unroll
    for(int g = 0; g < 8; ++g){
      f32x4 acc[3] = {z, z, z};
      #pragma unroll
      for(int ks = 0; ks < 3; ++ks){
        #pragma unroll
        for(int gg = 0; gg < 3; ++gg){
          bf16x8 bv = *(const bf16x8*)(w1T + (g*48 + gg*16 + ml)*96 + ks*32 + q*8);
          acc[gg] = MFMA16(av[ks], bv, acc[gg]);
        }
      }
      #pragma unroll
      for(int gg = 0; gg < 3; ++gg){
        int n = g*48 + gg*16 + ml;
        float bias = b1[n];
        #pragma unroll
        for(int r = 0; r < 4; ++r)
          hidL[(w*16 + q*4 + r)*392 + n] = bfr(fmaxf(acc[gg][r] + bias, 0.f));
      }
    }
  }
  __syncthreads();
  // GEMM2: 64x96, K=384 from LDS hidden
  f32x4 acc2[6];
  #pragma unroll
  for(int g=0; g<6; ++g) acc2[g] = z;
  {
    const unsigned short* arow = hidL + (w*16 + ml)*392;
    #pragma unroll
    for(int ks = 0; ks < 12; ++ks){
      bf16x8 av = *(const bf16x8*)(arow + ks*32 + q*8);
      #pragma unroll
      for(int g = 0; g < 6; ++g){
        bf16x8 bv = *(const bf16x8*)(w2T + (g*16 + ml)*384 + ks*32 + q*8);
        acc2[g] = MFMA16(av, bv, acc2[g]);
      }
    }
  }
  __syncthreads();      // hidL reads done; region becomes T
  #pragma unroll
  for(int g = 0; g < 6; ++g)
    #pragma unroll
    for(int r = 0; r < 4; ++r)
      T[(g*16 + ml)*68 + w*16 + q*4 + r] = acc2[g][r];
  __syncthreads();
  for(int idx = tid; idx < 96*64; idx += 256){
    int n = idx >> 6, px = idx & 63;
    float rsf = fmaf(m1w[n], stdv, m1b[n]);
    float rbf = fmaf(m2w[n], mean, m2b[n]);
    int ad = (b*CC + n)*NP + pxl0 + px;
    dst[ad] = ldf(scx, ad) + (T[n*68 + px] + b2[n])*rsf + rbf;
  }
}

// ---- fused m2a + ca: compute ca from gap, then BN*pa*ca -> GEMM1 -> gelu -> GEMM2 -> +x3 ----
__global__ void __launch_bounds__(256) gemm_m2a_kernel(
    const float* __restrict__ x3, const float* __restrict__ bns,
    const float* __restrict__ pa, const float* __restrict__ gap,
    const float* __restrict__ cw1T, const float* __restrict__ cb1,
    const float* __restrict__ cw2T, const float* __restrict__ cb2,
    const unsigned short* __restrict__ w1T, const float* __restrict__ b1,
    const unsigned short* __restrict__ w2T, const float* __restrict__ b2,
    const float* __restrict__ scx, float* __restrict__ outp){
  __shared__ __align__(16) char smbuf[26624];
  __shared__ float scl[96], ofs[96], pal[64];
  __shared__ float gl[96], tl[96];
  unsigned short* Atl = (unsigned short*)smbuf;
  unsigned short* tl2 = (unsigned short*)(smbuf + 13312);
  float* T = (float*)smbuf;
  int m_base = blockIdx.x*64;
  int b = m_base >> 12, pxl0 = m_base & 4095;
  int tid = threadIdx.x;
  // --- ca for this batch, from gap (transposed ca weights -> coalesced) ---
  if(tid < 96) gl[tid] = gap[b*96 + tid];
  if(tid >= 128 && tid < 192) pal[tid-128] = pa[m_base + (tid-128)];
  __syncthreads();
  if(tid < 96){
    float a = cb1[tid];
    #pragma unroll 8
    for(int c = 0; c < 96; ++c) a = fmaf(gl[c], cw1T[c*96 + tid], a);
    tl[tid] = gelu_f(a);
  }
  __syncthreads();
  if(tid < 96){
    float a = cb2[tid];
    #pragma unroll 8
    for(int c = 0; c < 96; ++c) a = fmaf(tl[c], cw2T[c*96 + tid], a);
    float cv = sigmoid_f(a);
    scl[tid] = bns[tid]*cv; ofs[tid] = bns[96+tid]*cv;
  }
  __syncthreads();
  const float* src = x3 + (size_t)b*CC*NP + pxl0;
  for(int idx = tid; idx < 96*16; idx += 256){
    int c = idx >> 4, p4 = (idx & 15) << 2;
    float4 v = *(const float4*)(src + (size_t)c*NP + p4);
    float s = scl[c], o = ofs[c];
    Atl[(p4+0)*104 + c] = bfr(fmaf(v.x, s, o) * pal[p4+0]);
    Atl[(p4+1)*104 + c] = bfr(fmaf(v.y, s, o) * pal[p4+1]);
    Atl[(p4+2)*104 + c] = bfr(fmaf(v.z, s, o) * pal[p4+2]);
    Atl[(p4+3)*104 + c] = bfr(fmaf(v.w, s, o) * pal[p4+3]);
  }
  __syncthreads();
  int w = tid >> 6, lane = tid & 63, ml = lane & 15, q = lane >> 4;
  f32x4 z = {0.f,0.f,0.f,0.f};
  f32x4 acc1[6];
  #pragma unroll
  for(int g=0; g<6; ++g) acc1[g] = z;
  {
    const unsigned short* arow = Atl + (w*16 + ml)*104;
    #pragma unroll
    for(int ks = 0; ks < 3; ++ks){
      bf16x8 av = *(const bf16x8*)(arow + ks*32 + q*8);
      #pragma unroll
      for(int g = 0; g < 6; ++g){
        bf16x8 bv = *(const bf16x8*)(w1T + (g*16 + ml)*96 + ks*32 + q*8);
        acc1[g] = MFMA16(av, bv, acc1[g]);
      }
    }
  }
  #pragma unroll
  for(int g = 0; g < 6; ++g){
    float bias = b1[g*16 + ml];
    #pragma unroll
    for(int r = 0; r < 4; ++r)
      tl2[(w*16 + q*4 + r)*104 + g*16 + ml] = bfr(gelu_f(acc1[g][r] + bias));
  }
  __syncthreads();
  f32x4 acc2[6];
  #pragma unroll
  for(int g=0; g<6; ++g) acc2[g] = z;
  {
    const unsigned short* arow = tl2 + (w*16 + ml)*104;
    #pragma unroll
    for(int ks = 0; ks < 3; ++ks){
      bf16x8 av = *(const bf16x8*)(arow + ks*32 + q*8);
      #pragma unroll
      for(int g = 0; g < 6; ++g){
        bf16x8 bv = *(const bf16x8*)(w2T + (g*16 + ml)*96 + ks*32 + q*8);
        acc2[g] = MFMA16(av, bv, acc2[g]);
      }
    }
  }
  __syncthreads();
  #pragma unroll
  for(int g = 0; g < 6; ++g)
    #pragma unroll
    for(int r = 0; r < 4; ++r)
      T[(g*16 + ml)*68 + w*16 + q*4 + r] = acc2[g][r];
  __syncthreads();
  for(int idx = tid; idx < 96*64; idx += 256){
    int n = idx >> 6, p = idx & 63;
    int ad = (b*CC + n)*NP + pxl0 + p;
    outp[ad] = scx[ad] + T[n*68 + p] + b2[n];
  }
}

// ---- neighborhood attention: bf16 LDS-staged k/v, output pixel-major bf16 ----
template<int K, int D, int RPB>
__global__ void __launch_bounds__(256) attn_kernel(
    const unsigned short* __restrict__ qb, const unsigned short* __restrict__ kb,
    const unsigned short* __restrict__ vb, const float* __restrict__ rpb,
    unsigned short* __restrict__ outp){
  int bh = blockIdx.x >> 6;
  int x = blockIdx.x & 63;
  int head = bh % NHEADS, b = bh / NHEADS;

  int gx = x % D, px = x / D;
  int Lgx = (64 - gx + D - 1) / D;
  int sx = min(max(px - K/2, 0), Lgx - K);

  __shared__ unsigned int sm[2*K*512];
  unsigned int* kl = sm;
  unsigned int* vl = sm + K*512;
  const unsigned int* kg = (const unsigned int*)(kb + (size_t)bh*NP*16);
  const unsigned int* vg = (const unsigned int*)(vb + (size_t)bh*NP*16);
  int tid = threadIdx.x;
  #pragma unroll
  for(int i = 0; i < K; ++i){
    int hh = gx + D*(sx + i);
    ((uint2*)(kl + i*512))[tid] = ((const uint2*)(kg + hh*512))[tid];
    ((uint2*)(vl + i*512))[tid] = ((const uint2*)(vg + hh*512))[tid];
  }
  __syncthreads();

  int pixoff = tid >> 2, t = tid & 3;
  int y = pixoff;
  int pix = x*64 + y;
  uint2 qd = *(const uint2*)(qb + ((size_t)bh*NP + pix)*16 + 4*t);
  float qx = bflo(qd.x), qy = bfhi(qd.x), qz = bflo(qd.y), qw = bfhi(qd.y);

  int gy = y % D, py = y / D;
  int Lgy = (64 - gy + D - 1) / D;
  int sy = min(max(py - K/2, 0), Lgy - K);

  float sc[K*K];
  #pragma unroll
  for(int i = 0; i < K; ++i){
    #pragma unroll
    for(int j = 0; j < K; ++j){
      int ww = gy + D*(sy + j);
      uint2 kv = *(const uint2*)(kl + i*512 + ww*8 + t*2);
      float s = qx*bflo(kv.x);
      s = fmaf(qy, bfhi(kv.x), s);
      s = fmaf(qz, bflo(kv.y), s);
      s = fmaf(qw, bfhi(kv.y), s);
      sc[i*K + j] = s;
    }
  }
  float mx = -1e30f;
  #pragma unroll
  for(int i = 0; i < K; ++i){
    const float* brow = rpb + (head*RPB + (sx + i - px + (K-1)))*RPB + (sy - py + (K-1));
    #pragma unroll
    for(int j = 0; j < K; ++j){
      float s = sc[i*K + j];
      s += __shfl_xor(s, 1);
      s += __shfl_xor(s, 2);
      s += brow[j];
      sc[i*K + j] = s;
      mx = fmaxf(mx, s);
    }
  }
  float sum = 0.f;
  #pragma unroll
  for(int n = 0; n < K*K; ++n){ float e = __expf(sc[n] - mx); sc[n] = e; sum += e; }
  float rs = 1.0f / sum;
  float4 acc = {0,0,0,0};
  #pragma unroll
  for(int i = 0; i < K; ++i){
    #pragma unroll
    for(int j = 0; j < K; ++j){
      int ww = gy + D*(sy + j);
      float wgt = sc[i*K + j] * rs;
      uint2 vv = *(const uint2*)(vl + i*512 + ww*8 + t*2);
      acc.x = fmaf(wgt, bflo(vv.x), acc.x);
      acc.y = fmaf(wgt, bfhi(vv.x), acc.y);
      acc.z = fmaf(wgt, bflo(vv.y), acc.z);
      acc.w = fmaf(wgt, bfhi(vv.y), acc.w);
    }
  }
  ushort4 o4;
  o4.x = bfr(acc.x); o4.y = bfr(acc.y); o4.z = bfr(acc.z); o4.w = bfr(acc.w);
  *(ushort4*)(outp + ((size_t)(b*NP + pix))*96 + head*16 + 4*t) = o4;
}

// ---- fused pixel attention + gap partials: 256 blocks, 4 lanes/pixel ----
__global__ void __launch_bounds__(256) pa_gap_kernel(
    const float* __restrict__ x3, const float* __restrict__ bns,
    const float* __restrict__ w1t, const float* __restrict__ b1,
    const float* __restrict__ w2, const float* __restrict__ b2,
    float* __restrict__ pa, float* __restrict__ gap){
  int b = blockIdx.x >> 6;
  int px0 = (blockIdx.x & 63)*64;
  int pxq = threadIdx.x >> 2, t = threadIdx.x & 3;
  int p = px0 + pxq;
  float yvv[24];
  float acc[12];
  #pragma unroll
  for(int h = 0; h < 12; ++h) acc[h] = 0.f;
  #pragma unroll 6
  for(int cc = 0; cc < 24; ++cc){
    int c = t*24 + cc;
    float yv = fmaf(x3[(b*CC + c)*NP + p], bns[c], bns[96 + c]);
    yvv[cc] = yv;
    #pragma unroll
    for(int h = 0; h < 12; ++h) acc[h] = fmaf(yv, w1t[c*12 + h], acc[h]);
  }
  #pragma unroll
  for(int h = 0; h < 12; ++h){
    acc[h] += __shfl_xor(acc[h], 1);
    acc[h] += __shfl_xor(acc[h], 2);
  }
  float s = b2[0];
  #pragma unroll
  for(int h = 0; h < 12; ++h) s = fmaf(gelu_f(acc[h] + b1[h]), w2[h], s);
  float pav = sigmoid_f(s);
  if(t == 0) pa[b*NP + p] = pav;
  __shared__ float gpart[4*96];
  int w = threadIdx.x >> 6, lane = threadIdx.x & 63;
  #pragma unroll 6
  for(int cc = 0; cc < 24; ++cc){
    float g = yvv[cc] * pav;
    g += __shfl_xor(g, 4);  g += __shfl_xor(g, 8);
    g += __shfl_xor(g, 16); g += __shfl_xor(g, 32);
    if(lane < 4 && lane == t) gpart[w*96 + t*24 + cc] = g;
  }
  __syncthreads();
  if(threadIdx.x < 96){
    int c = threadIdx.x;
    float v = (gpart[c] + gpart[96+c] + gpart[192+c] + gpart[288+c]) * (1.0f/4096.0f);
    atomicAdd(&gap[b*96 + c], v);
  }
}

extern "C" void kernel_launch(void* const* d_in, const int* in_sizes, int n_in,
                              void* d_out, int out_size, void* d_ws, size_t ws_size,
                              hipStream_t stream){
  (void)in_sizes; (void)n_in; (void)out_size; (void)ws_size;
  const float* x     = (const float*)d_in[0];
  const float* lnw   = (const float*)d_in[1];
  const float* lnb   = (const float*)d_in[2];
  const float* m1w   = (const float*)d_in[3];
  const float* m1b   = (const float*)d_in[4];
  const float* m2w   = (const float*)d_in[5];
  const float* m2b   = (const float*)d_in[6];
  const float* qkv1w = (const float*)d_in[7];
  const float* qkv1b = (const float*)d_in[8];
  const float* proj1w= (const float*)d_in[9];
  const float* proj1b= (const float*)d_in[10];
  const float* rpb1  = (const float*)d_in[11];
  const float* qkv2w = (const float*)d_in[12];
  const float* qkv2b = (const float*)d_in[13];
  const float* proj2w= (const float*)d_in[14];
  const float* proj2b= (const float*)d_in[15];
  const float* rpb2  = (const float*)d_in[16];
  const float* mw1   = (const float*)d_in[17];
  const float* mb1   = (const float*)d_in[18];
  const float* mw2   = (const float*)d_in[19];
  const float* mb2   = (const float*)d_in[20];
  const float* bng   = (const float*)d_in[21];
  const float* bnb   = (const float*)d_in[22];
  const float* bnm   = (const float*)d_in[23];
  const float* bnv   = (const float*)d_in[24];
  const float* paw1  = (const float*)d_in[25];
  const float* pab1  = (const float*)d_in[26];
  const float* paw2  = (const float*)d_in[27];
  const float* pab2  = (const float*)d_in[28];
  const float* caw1  = (const float*)d_in[29];
  const float* cab1  = (const float*)d_in[30];
  const float* caw2  = (const float*)d_in[31];
  const float* cab2  = (const float*)d_in[32];
  const float* aw1   = (const float*)d_in[33];
  const float* ab1   = (const float*)d_in[34];
  const float* aw2   = (const float*)d_in[35];
  const float* ab2   = (const float*)d_in[36];

  float* ws  = (float*)d_ws;
  float* out = (float*)d_out;
  float* st0 = ws;
  float* st1 = ws + 8;
  float* st2 = ws + 16;
  unsigned short* q     = (unsigned short*)(ws + WS_Q);
  unsigned short* k     = (unsigned short*)(ws + WS_K);
  unsigned short* v     = (unsigned short*)(ws + WS_V);
  unsigned short* attpm = (unsigned short*)(ws + WS_ATTPM);
  unsigned short* x1b   = (unsigned short*)(ws + WS_X1);
  unsigned short* x2b   = (unsigned short*)(ws + WS_X2);
  float* x3  = ws + WS_X3;
  float* pab = ws + WS_PA;
  float* gpb = ws + WS_GAP;
  float* bns = ws + WBNS;

  hipMemsetAsync(d_ws, 0, 64*sizeof(float), stream);
  prep_stats_kernel<<<1111, 256, 0, stream>>>(x, st0, qkv1w, qkv2w, proj1w, proj2w,
                                              mw1, mw2, aw1, aw2, paw1,
                                              bng, bnb, bnm, bnv, caw1, caw2, ws);

  // stage 1: attn k=7 d=1
  gemm_qkv_kernel<float><<<256, 256, 0, stream>>>(x, st0, lnw, lnb,
      (unsigned short*)(ws+WQKV1), qkv1b, q, k, v);
  attn_kernel<7,1,13><<<1536, 256, 0, stream>>>(q, k, v, rpb1, attpm);
  gemm_proj_kernel<float><<<dim3(128,2), 256, 0, stream>>>(attpm, (unsigned short*)(ws+WPROJ1),
      proj1b, x, st0, m1w, m1b, m2w, m2b, x1b, st1);

  // stage 2: attn k=5 d=8
  gemm_qkv_kernel<unsigned short><<<256, 256, 0, stream>>>(x1b, st1, lnw, lnb,
      (unsigned short*)(ws+WQKV2), qkv2b, q, k, v);
  attn_kernel<5,8,9><<<1536, 256, 0, stream>>>(q, k, v, rpb2, attpm);
  gemm_proj_kernel<unsigned short><<<dim3(128,2), 256, 0, stream>>>(attpm, (unsigned short*)(ws+WPROJ2),
      proj2b, x1b, st1, m1w, m1b, m2w, m2b, x2b, st2);

  // stage 3: fused MLP (sc = x1)
  gemm_mlp_kernel<<<256, 256, 0, stream>>>(x2b, st2, lnw, lnb,
      (unsigned short*)(ws+WMLP1), mb1, (unsigned short*)(ws+WMLP2), mb2,
      x1b, m1w, m1b, m2w, m2b, x3);

  // stage 4: pa(+gap) -> fused (ca + m2a)
  pa_gap_kernel<<<256, 256, 0, stream>>>(x3, bns, ws + WPA1T, pab1, paw2, pab2, pab, gpb);
  gemm_m2a_kernel<<<256, 256, 0, stream>>>(x3, bns, pab, gpb,
                                           ws + WCA1T, cab1, ws + WCA2T, cab2,
                                           (unsigned short*)(ws+WM2A1), ab1,
                                           (unsigned short*)(ws+WM2A2), ab2, x3, out);
}